// Round 1
// baseline (2185.376 us; speedup 1.0000x reference)
//
#include <hip/hip_runtime.h>
#include <math.h>

#define TSEQ 1024
#define DMODEL 1024
#define NH 16
#define HD 64
#define RANK 32

// ---------------- generic fp32 tiled GEMM: C[M,N] = A[M,K] @ B[K,N] ----------------
// 64x64 tile per block, 256 threads, 4x4 microtile, BK=16. Requires M,N %64==0, K%16==0.
__global__ __launch_bounds__(256) void gemm_f32(const float* __restrict__ A,
    const float* __restrict__ B, float* __restrict__ C, int M, int N, int K)
{
    __shared__ float At[16][68];   // [k][i] transposed
    __shared__ float Bs[16][68];   // [k][j]
    const int tid = threadIdx.x;
    const int tx = tid & 15, ty = tid >> 4;
    const int i0 = blockIdx.y * 64, j0 = blockIdx.x * 64;
    const int arow = tid >> 2, ac4 = (tid & 3) * 4;
    const int brow = tid >> 4, bc4 = (tid & 15) * 4;
    float acc[4][4] = {};
    for (int k0 = 0; k0 < K; k0 += 16) {
        float4 a = *(const float4*)&A[(size_t)(i0 + arow) * K + k0 + ac4];
        At[ac4 + 0][arow] = a.x; At[ac4 + 1][arow] = a.y;
        At[ac4 + 2][arow] = a.z; At[ac4 + 3][arow] = a.w;
        *(float4*)&Bs[brow][bc4] = *(const float4*)&B[(size_t)(k0 + brow) * N + j0 + bc4];
        __syncthreads();
        #pragma unroll
        for (int kk = 0; kk < 16; ++kk) {
            float4 a4 = *(const float4*)&At[kk][ty * 4];
            float4 b4 = *(const float4*)&Bs[kk][tx * 4];
            float av[4] = {a4.x, a4.y, a4.z, a4.w};
            float bv[4] = {b4.x, b4.y, b4.z, b4.w};
            #pragma unroll
            for (int m = 0; m < 4; ++m)
                #pragma unroll
                for (int n = 0; n < 4; ++n)
                    acc[m][n] = fmaf(av[m], bv[n], acc[m][n]);
        }
        __syncthreads();
    }
    #pragma unroll
    for (int m = 0; m < 4; ++m) {
        float4 o = {acc[m][0], acc[m][1], acc[m][2], acc[m][3]};
        *(float4*)&C[(size_t)(i0 + ty * 4 + m) * N + j0 + tx * 4] = o;
    }
}

// ---------------- skinny GEMM (N<=64): one thread per output ----------------
__global__ void gemm_skinny(const float* __restrict__ A, const float* __restrict__ B,
                            float* __restrict__ C, int M, int N, int K)
{
    int idx = blockIdx.x * blockDim.x + threadIdx.x;
    if (idx >= M * N) return;
    int row = idx / N, col = idx - row * N;
    const float* a = A + (size_t)row * K;
    float s = 0.f;
    for (int k = 0; k < K; ++k) s = fmaf(a[k], B[(size_t)k * N + col], s);
    C[idx] = s;
}

// ---------------- causal depthwise conv(3) + SiLU + per-head L2 norm + beta ----------------
// one wave per (t, h); lane = channel-within-head
__global__ __launch_bounds__(64) void conv_silu_norm(const float* __restrict__ wpre,
    const float* __restrict__ cw, const float* __restrict__ blog,
    float* __restrict__ w, float* __restrict__ beta)
{
    const int t = blockIdx.x, h = blockIdx.y, d = threadIdx.x;
    const int c = h * HD + d;
    float x2 = wpre[(size_t)t * DMODEL + c];
    float x1 = (t >= 1) ? wpre[(size_t)(t - 1) * DMODEL + c] : 0.f;
    float x0 = (t >= 2) ? wpre[(size_t)(t - 2) * DMODEL + c] : 0.f;
    float y = cw[c * 3 + 0] * x0 + cw[c * 3 + 1] * x1 + cw[c * 3 + 2] * x2;
    y = y / (1.f + expf(-y));            // SiLU
    float ss = y * y;
    #pragma unroll
    for (int off = 32; off >= 1; off >>= 1) ss += __shfl_xor(ss, off, 64);
    float r = 1.f / sqrtf(ss + 1e-6f);
    w[(size_t)t * DMODEL + c] = y * r;
    if (d == 0) beta[t * NH + h] = 2.f / (1.f + expf(-blog[t * NH + h]));
}

// ---------------- pairwise dots over head dim (K=64) ----------------
// C[hh][i][j] = mask * scale_i * dot(A[i, h-slice], B[j, h-slice])
// mode 0: causal (i>=j), no scale; mode 1: strict (i>j), scale rows by beta[i].
// Upper-strict tiles are skipped; masked entries inside written tiles are ZERO
// (downstream GEMMs rely on those stored zeros).
__global__ __launch_bounds__(256) void pairwise64(const float* __restrict__ A,
    const float* __restrict__ B, const float* __restrict__ beta,
    float* __restrict__ C, int mode, int h0)
{
    const int jt = blockIdx.x, it = blockIdx.y, hh = blockIdx.z;
    if (jt > it) return;
    const int h = h0 + hh;
    __shared__ float Atile[64][68];  // [d][i]
    __shared__ float Btile[64][68];  // [d][j]
    const int tid = threadIdx.x;
    const int tx = tid & 15, ty = tid >> 4;
    const int i0 = it * 64, j0 = jt * 64;
    const int row = tid >> 2, c4 = (tid & 3) * 4;
    #pragma unroll
    for (int p = 0; p < 4; ++p) {
        int dd = c4 + p * 16;
        float4 a = *(const float4*)&A[(size_t)(i0 + row) * DMODEL + h * HD + dd];
        Atile[dd + 0][row] = a.x; Atile[dd + 1][row] = a.y;
        Atile[dd + 2][row] = a.z; Atile[dd + 3][row] = a.w;
        float4 b = *(const float4*)&B[(size_t)(j0 + row) * DMODEL + h * HD + dd];
        Btile[dd + 0][row] = b.x; Btile[dd + 1][row] = b.y;
        Btile[dd + 2][row] = b.z; Btile[dd + 3][row] = b.w;
    }
    __syncthreads();
    float acc[4][4] = {};
    #pragma unroll 8
    for (int kk = 0; kk < 64; ++kk) {
        float4 a4 = *(const float4*)&Atile[kk][ty * 4];
        float4 b4 = *(const float4*)&Btile[kk][tx * 4];
        float av[4] = {a4.x, a4.y, a4.z, a4.w};
        float bv[4] = {b4.x, b4.y, b4.z, b4.w};
        #pragma unroll
        for (int m = 0; m < 4; ++m)
            #pragma unroll
            for (int n = 0; n < 4; ++n)
                acc[m][n] = fmaf(av[m], bv[n], acc[m][n]);
    }
    float* Ch = C + (size_t)hh * TSEQ * TSEQ;
    #pragma unroll
    for (int m = 0; m < 4; ++m) {
        int i = i0 + ty * 4 + m;
        float sc = (mode == 1) ? beta[i * NH + h] : 1.f;
        float v[4];
        #pragma unroll
        for (int n = 0; n < 4; ++n) {
            int j = j0 + tx * 4 + n;
            bool keep = mode ? (i > j) : (i >= j);
            v[n] = keep ? acc[m][n] * sc : 0.f;
        }
        float4 o = {v[0], v[1], v[2], v[3]};
        *(float4*)&Ch[(size_t)i * TSEQ + j0 + tx * 4] = o;
    }
}

// ---------------- blocked triangular solve step for column-chunk c ----------------
// Solves G (I+M) = QW in place (G buffer initially holds causal-masked QW).
// Chunks processed c = 15 .. 0 by successive launches.
// Phase A: acc = sum_{c'=c+1..rt} G[rows, c'] @ M[c', c]   (dense 64^3 tile GEMMs)
// Phase B: backward substitution vs unit-lower diag block M[c,c] (one row per wave).
__global__ __launch_bounds__(256) void solve_chunk(float* __restrict__ G,
    const float* __restrict__ Mm, int c)
{
    const int rt = c + blockIdx.x;       // row tile in [c, 15]
    const int hh = blockIdx.y;
    float* Gh = G + (size_t)hh * TSEQ * TSEQ;
    const float* Mh = Mm + (size_t)hh * TSEQ * TSEQ;
    __shared__ float T0[64][68];         // phase A: G^T [s][i]; phase B: RHS [i][j]
    __shared__ float T1[64][68];         // M [s][j]; phase B: Mcc [s][j]
    const int tid = threadIdx.x, tx = tid & 15, ty = tid >> 4;
    const int i0 = rt * 64, j0 = c * 64;
    const int row = tid >> 2, c4 = (tid & 3) * 4;
    float acc[4][4] = {};
    for (int cp = c + 1; cp <= rt; ++cp) {
        const int s0 = cp * 64;
        #pragma unroll
        for (int p = 0; p < 4; ++p) {
            int dd = c4 + p * 16;
            float4 g = *(const float4*)&Gh[(size_t)(i0 + row) * TSEQ + s0 + dd];
            T0[dd + 0][row] = g.x; T0[dd + 1][row] = g.y;
            T0[dd + 2][row] = g.z; T0[dd + 3][row] = g.w;
            *(float4*)&T1[row][dd] = *(const float4*)&Mh[(size_t)(s0 + row) * TSEQ + j0 + dd];
        }
        __syncthreads();
        #pragma unroll 8
        for (int kk = 0; kk < 64; ++kk) {
            float4 a4 = *(const float4*)&T0[kk][ty * 4];
            float4 b4 = *(const float4*)&T1[kk][tx * 4];
            float av[4] = {a4.x, a4.y, a4.z, a4.w};
            float bv[4] = {b4.x, b4.y, b4.z, b4.w};
            #pragma unroll
            for (int m = 0; m < 4; ++m)
                #pragma unroll
                for (int n = 0; n < 4; ++n)
                    acc[m][n] = fmaf(av[m], bv[n], acc[m][n]);
        }
        __syncthreads();
    }
    // RHS = current(QW) - acc  -> T0 as [i][j]
    #pragma unroll
    for (int m = 0; m < 4; ++m)
        #pragma unroll
        for (int n = 0; n < 4; ++n)
            T0[ty * 4 + m][tx * 4 + n] =
                Gh[(size_t)(i0 + ty * 4 + m) * TSEQ + j0 + tx * 4 + n] - acc[m][n];
    // Mcc (unit-diag block, strict-lower values, zeros elsewhere)
    #pragma unroll
    for (int p = 0; p < 4; ++p) {
        int dd = c4 + p * 16;
        *(float4*)&T1[row][dd] = *(const float4*)&Mh[(size_t)(j0 + row) * TSEQ + j0 + dd];
    }
    __syncthreads();
    // per-row backward substitution: G[i][s] = RHS[i][s] - sum_{s'>s} G[i][s'] Mcc[s'][s]
    const int wv = tid >> 6, lane = tid & 63;
    for (int qr = 0; qr < 16; ++qr) {
        const int r_ = wv * 16 + qr;
        float rv = T0[r_][lane];
        for (int s = 63; s >= 1; --s) {
            float g = __shfl(rv, s, 64);
            if (lane < s) rv = fmaf(-g, T1[s][lane], rv);
        }
        Gh[(size_t)(i0 + r_) * TSEQ + j0 + lane] = rv;
    }
}

// ---------------- S -= G @ Mk  (triangular-tile GEMM) ----------------
__global__ __launch_bounds__(256) void s_update(float* __restrict__ S,
    const float* __restrict__ G, const float* __restrict__ Mk)
{
    const int jt = blockIdx.x, it = blockIdx.y, hh = blockIdx.z;
    if (jt > it) return;
    const float* Gh = G + (size_t)hh * TSEQ * TSEQ;
    const float* Mh = Mk + (size_t)hh * TSEQ * TSEQ;
    float* Sh = S + (size_t)hh * TSEQ * TSEQ;
    __shared__ float Gt[64][68];  // [s][i]
    __shared__ float Ms[64][68];  // [s][j]
    const int tid = threadIdx.x, tx = tid & 15, ty = tid >> 4;
    const int i0 = it * 64, j0 = jt * 64;
    const int row = tid >> 2, c4 = (tid & 3) * 4;
    float acc[4][4] = {};
    for (int st = jt; st <= it; ++st) {   // stored zeros handle s<=j and s>i edges
        const int s0 = st * 64;
        #pragma unroll
        for (int p = 0; p < 4; ++p) {
            int dd = c4 + p * 16;
            float4 g = *(const float4*)&Gh[(size_t)(i0 + row) * TSEQ + s0 + dd];
            Gt[dd + 0][row] = g.x; Gt[dd + 1][row] = g.y;
            Gt[dd + 2][row] = g.z; Gt[dd + 3][row] = g.w;
            *(float4*)&Ms[row][dd] = *(const float4*)&Mh[(size_t)(s0 + row) * TSEQ + j0 + dd];
        }
        __syncthreads();
        #pragma unroll 8
        for (int kk = 0; kk < 64; ++kk) {
            float4 a4 = *(const float4*)&Gt[kk][ty * 4];
            float4 b4 = *(const float4*)&Ms[kk][tx * 4];
            float av[4] = {a4.x, a4.y, a4.z, a4.w};
            float bv[4] = {b4.x, b4.y, b4.z, b4.w};
            #pragma unroll
            for (int m = 0; m < 4; ++m)
                #pragma unroll
                for (int n = 0; n < 4; ++n)
                    acc[m][n] = fmaf(av[m], bv[n], acc[m][n]);
        }
        __syncthreads();
    }
    #pragma unroll
    for (int m = 0; m < 4; ++m) {
        float* p = &Sh[(size_t)(i0 + ty * 4 + m) * TSEQ + j0 + tx * 4];
        float4 sv = *(float4*)p;
        sv.x -= acc[m][0]; sv.y -= acc[m][1]; sv.z -= acc[m][2]; sv.w -= acc[m][3];
        *(float4*)p = sv;
    }
}

// ---------------- causal row softmax with D^-0.5 scaling, in place ----------------
__global__ __launch_bounds__(256) void softmax_causal(float* __restrict__ S)
{
    const int i = blockIdx.x, hh = blockIdx.y;
    float* row = S + (size_t)hh * TSEQ * TSEQ + (size_t)i * TSEQ;
    const int tid = threadIdx.x;
    const float sc = 0.125f;  // 64^-0.5
    __shared__ float red[256];
    float mx = -3.4e38f;
    for (int j = tid; j <= i; j += 256) mx = fmaxf(mx, row[j] * sc);
    red[tid] = mx; __syncthreads();
    for (int off = 128; off >= 1; off >>= 1) {
        if (tid < off) red[tid] = fmaxf(red[tid], red[tid + off]);
        __syncthreads();
    }
    mx = red[0]; __syncthreads();
    float sum = 0.f;
    for (int j = tid; j <= i; j += 256) {
        float e = expf(row[j] * sc - mx);
        row[j] = e; sum += e;
    }
    red[tid] = sum; __syncthreads();
    for (int off = 128; off >= 1; off >>= 1) {
        if (tid < off) red[tid] += red[tid + off];
        __syncthreads();
    }
    float inv = 1.f / red[0];
    for (int j = tid; j <= i; j += 256) row[j] *= inv;
}

// ---------------- O[head slice] = P @ V ----------------
__global__ __launch_bounds__(256) void pv64(const float* __restrict__ P,
    const float* __restrict__ V, float* __restrict__ O, int h0)
{
    const int it = blockIdx.x, hh = blockIdx.y, h = h0 + hh;
    const float* Ph = P + (size_t)hh * TSEQ * TSEQ;
    __shared__ float Pt[64][68];  // [j][i]
    __shared__ float Vs[64][68];  // [j][d]
    const int tid = threadIdx.x, tx = tid & 15, ty = tid >> 4;
    const int i0 = it * 64;
    const int row = tid >> 2, c4 = (tid & 3) * 4;
    float acc[4][4] = {};
    for (int jt = 0; jt <= it; ++jt) {
        const int j0 = jt * 64;
        const int i = i0 + row;
        #pragma unroll
        for (int p = 0; p < 4; ++p) {
            int dd = c4 + p * 16;
            float4 pv = *(const float4*)&Ph[(size_t)i * TSEQ + j0 + dd];
            Pt[dd + 0][row] = (j0 + dd + 0 <= i) ? pv.x : 0.f;
            Pt[dd + 1][row] = (j0 + dd + 1 <= i) ? pv.y : 0.f;
            Pt[dd + 2][row] = (j0 + dd + 2 <= i) ? pv.z : 0.f;
            Pt[dd + 3][row] = (j0 + dd + 3 <= i) ? pv.w : 0.f;
            *(float4*)&Vs[row][dd] = *(const float4*)&V[(size_t)(j0 + row) * DMODEL + h * HD + dd];
        }
        __syncthreads();
        #pragma unroll 8
        for (int kk = 0; kk < 64; ++kk) {
            float4 a4 = *(const float4*)&Pt[kk][ty * 4];
            float4 b4 = *(const float4*)&Vs[kk][tx * 4];
            float av[4] = {a4.x, a4.y, a4.z, a4.w};
            float bv[4] = {b4.x, b4.y, b4.z, b4.w};
            #pragma unroll
            for (int m = 0; m < 4; ++m)
                #pragma unroll
                for (int n = 0; n < 4; ++n)
                    acc[m][n] = fmaf(av[m], bv[n], acc[m][n]);
        }
        __syncthreads();
    }
    #pragma unroll
    for (int m = 0; m < 4; ++m) {
        float4 o = {acc[m][0], acc[m][1], acc[m][2], acc[m][3]};
        *(float4*)&O[(size_t)(i0 + ty * 4 + m) * DMODEL + h * HD + tx * 4] = o;
    }
}

extern "C" void kernel_launch(void* const* d_in, const int* in_sizes, int n_in,
                              void* d_out, int out_size, void* d_ws, size_t ws_size,
                              hipStream_t stream)
{
    const float* x   = (const float*)d_in[0];
    const float* Wq  = (const float*)d_in[1];
    const float* Wk  = (const float*)d_in[2];
    const float* Wv  = (const float*)d_in[3];
    const float* Ww1 = (const float*)d_in[4];
    const float* Ww2 = (const float*)d_in[5];
    const float* cw  = (const float*)d_in[6];
    const float* Wb  = (const float*)d_in[7];
    const float* Wo  = (const float*)d_in[8];
    float* out = (float*)d_out;

    float* ws = (float*)d_ws;
    size_t off = 0;
    auto alloc = [&](size_t n) { float* p = ws + off; off += n; return p; };
    float* q    = alloc((size_t)TSEQ * DMODEL);
    float* k    = alloc((size_t)TSEQ * DMODEL);
    float* v    = alloc((size_t)TSEQ * DMODEL);
    float* w    = alloc((size_t)TSEQ * DMODEL);
    float* wpre = alloc((size_t)TSEQ * DMODEL);
    float* oatt = alloc((size_t)TSEQ * DMODEL);
    float* xw1  = alloc((size_t)TSEQ * RANK);
    float* blog = alloc((size_t)TSEQ * NH);
    float* beta = alloc((size_t)TSEQ * NH);

    // Big per-head-group buffers: S, G(QW), M(->Mk). Pick largest head group
    // that fits ws_size (deterministic: ws_size is constant for the session).
    int HG = NH;
    while (HG > 1 && (off + 3ull * HG * TSEQ * TSEQ) * sizeof(float) > ws_size) HG >>= 1;
    float* Sb = alloc((size_t)HG * TSEQ * TSEQ);
    float* Gb = alloc((size_t)HG * TSEQ * TSEQ);
    float* Mb = alloc((size_t)HG * TSEQ * TSEQ);

    dim3 g64(DMODEL / 64, TSEQ / 64);
    gemm_f32<<<g64, 256, 0, stream>>>(x, Wq, q, TSEQ, DMODEL, DMODEL);
    gemm_f32<<<g64, 256, 0, stream>>>(x, Wk, k, TSEQ, DMODEL, DMODEL);
    gemm_f32<<<g64, 256, 0, stream>>>(x, Wv, v, TSEQ, DMODEL, DMODEL);
    gemm_skinny<<<(TSEQ * RANK + 255) / 256, 256, 0, stream>>>(x, Ww1, xw1, TSEQ, RANK, DMODEL);
    gemm_f32<<<g64, 256, 0, stream>>>(xw1, Ww2, wpre, TSEQ, DMODEL, RANK);
    gemm_skinny<<<(TSEQ * NH + 255) / 256, 256, 0, stream>>>(x, Wb, blog, TSEQ, NH, DMODEL);
    conv_silu_norm<<<dim3(TSEQ, NH), 64, 0, stream>>>(wpre, cw, blog, w, beta);

    for (int h0 = 0; h0 < NH; h0 += HG) {
        dim3 gp(16, 16, HG);
        pairwise64<<<gp, 256, 0, stream>>>(w, w, beta, Mb, 1, h0);      // M  (strict, beta)
        pairwise64<<<gp, 256, 0, stream>>>(q, w, nullptr, Gb, 0, h0);   // QW (causal) -> RHS
        pairwise64<<<gp, 256, 0, stream>>>(q, k, nullptr, Sb, 0, h0);   // QK (causal)
        for (int c = 15; c >= 0; --c)
            solve_chunk<<<dim3(16 - c, HG), 256, 0, stream>>>(Gb, Mb, c);
        pairwise64<<<gp, 256, 0, stream>>>(w, k, beta, Mb, 1, h0);      // Mk (strict, beta), reuse M buf
        s_update<<<gp, 256, 0, stream>>>(Sb, Gb, Mb);                   // S = QK - G Mk
        softmax_causal<<<dim3(TSEQ, HG), 256, 0, stream>>>(Sb);
        pv64<<<dim3(16, HG), 256, 0, stream>>>(Sb, v, oatt, h0);
    }
    gemm_f32<<<g64, 256, 0, stream>>>(oatt, Wo, out, TSEQ, DMODEL, DMODEL);
}

// Round 4
// 1806.102 us; speedup vs baseline: 1.2100x; 1.2100x over previous
//
#include <hip/hip_runtime.h>
#include <math.h>

#define TSEQ 1024
#define DMODEL 1024
#define NH 16
#define HD 64
#define RANK 32

// ---------------- generic fp32 tiled GEMM: C[M,N] = A[M,K] @ B[K,N] ----------------
// 64x64 tile per block, 256 threads, 4x4 microtile, BK=16. Requires M,N %64==0, K%16==0.
__global__ __launch_bounds__(256) void gemm_f32(const float* __restrict__ A,
    const float* __restrict__ B, float* __restrict__ C, int M, int N, int K)
{
    __shared__ float At[16][68];   // [k][i] transposed
    __shared__ float Bs[16][68];   // [k][j]
    const int tid = threadIdx.x;
    const int tx = tid & 15, ty = tid >> 4;
    const int i0 = blockIdx.y * 64, j0 = blockIdx.x * 64;
    const int arow = tid >> 2, ac4 = (tid & 3) * 4;
    const int brow = tid >> 4, bc4 = (tid & 15) * 4;
    float acc[4][4] = {};
    for (int k0 = 0; k0 < K; k0 += 16) {
        float4 a = *(const float4*)&A[(size_t)(i0 + arow) * K + k0 + ac4];
        At[ac4 + 0][arow] = a.x; At[ac4 + 1][arow] = a.y;
        At[ac4 + 2][arow] = a.z; At[ac4 + 3][arow] = a.w;
        *(float4*)&Bs[brow][bc4] = *(const float4*)&B[(size_t)(k0 + brow) * N + j0 + bc4];
        __syncthreads();
        #pragma unroll
        for (int kk = 0; kk < 16; ++kk) {
            float4 a4 = *(const float4*)&At[kk][ty * 4];
            float4 b4 = *(const float4*)&Bs[kk][tx * 4];
            float av[4] = {a4.x, a4.y, a4.z, a4.w};
            float bv[4] = {b4.x, b4.y, b4.z, b4.w};
            #pragma unroll
            for (int m = 0; m < 4; ++m)
                #pragma unroll
                for (int n = 0; n < 4; ++n)
                    acc[m][n] = fmaf(av[m], bv[n], acc[m][n]);
        }
        __syncthreads();
    }
    #pragma unroll
    for (int m = 0; m < 4; ++m) {
        float4 o = {acc[m][0], acc[m][1], acc[m][2], acc[m][3]};
        *(float4*)&C[(size_t)(i0 + ty * 4 + m) * N + j0 + tx * 4] = o;
    }
}

// ---------------- skinny GEMM (N in {16,32}, power of 2): row-parallel split-K ----
// one block per output row; thread t: col = t & (N-1), k-slice = t / N (256/N slices)
__global__ __launch_bounds__(256) void gemm_skinny_rows(const float* __restrict__ A,
    const float* __restrict__ B, float* __restrict__ C, int N, int K)
{
    const int row = blockIdx.x;
    const int tid = threadIdx.x;
    const int col = tid & (N - 1);
    const int ks = tid / N;
    const int nsl = 256 / N;
    const float* a = A + (size_t)row * K;
    float s = 0.f;
    for (int k = ks; k < K; k += nsl)
        s = fmaf(a[k], B[(size_t)k * N + col], s);
    __shared__ float red[256];
    red[tid] = s; __syncthreads();
    for (int off = 128; off >= N; off >>= 1) {
        if (tid < off) red[tid] += red[tid + off];
        __syncthreads();
    }
    if (tid < N) C[(size_t)row * N + col] = red[tid];
}

// ---------------- causal depthwise conv(3) + SiLU + per-head L2 norm + beta ----------------
// one wave per (t, h); lane = channel-within-head
__global__ __launch_bounds__(64) void conv_silu_norm(const float* __restrict__ wpre,
    const float* __restrict__ cw, const float* __restrict__ blog,
    float* __restrict__ w, float* __restrict__ beta)
{
    const int t = blockIdx.x, h = blockIdx.y, d = threadIdx.x;
    const int c = h * HD + d;
    float x2 = wpre[(size_t)t * DMODEL + c];
    float x1 = (t >= 1) ? wpre[(size_t)(t - 1) * DMODEL + c] : 0.f;
    float x0 = (t >= 2) ? wpre[(size_t)(t - 2) * DMODEL + c] : 0.f;
    float y = cw[c * 3 + 0] * x0 + cw[c * 3 + 1] * x1 + cw[c * 3 + 2] * x2;
    y = y / (1.f + expf(-y));            // SiLU
    float ss = y * y;
    #pragma unroll
    for (int off = 32; off >= 1; off >>= 1) ss += __shfl_xor(ss, off, 64);
    float r = 1.f / sqrtf(ss + 1e-6f);
    w[(size_t)t * DMODEL + c] = y * r;
    if (d == 0) beta[t * NH + h] = 2.f / (1.f + expf(-blog[t * NH + h]));
}

// ---------------- pairwise dots over head dim (K=64) ----------------
// C[hh][i][j] = mask * scale_i * dot(A[i, h-slice], B[j, h-slice])
// mode 0: causal (i>=j), no scale; mode 1: strict (i>j), scale rows by beta[i].
// Upper-strict tiles are skipped; masked entries inside written tiles are ZERO
// (downstream GEMMs rely on those stored zeros).
__global__ __launch_bounds__(256) void pairwise64(const float* __restrict__ A,
    const float* __restrict__ B, const float* __restrict__ beta,
    float* __restrict__ C, int mode, int h0)
{
    const int jt = blockIdx.x, it = blockIdx.y, hh = blockIdx.z;
    if (jt > it) return;
    const int h = h0 + hh;
    __shared__ float Atile[64][68];  // [d][i]
    __shared__ float Btile[64][68];  // [d][j]
    const int tid = threadIdx.x;
    const int tx = tid & 15, ty = tid >> 4;
    const int i0 = it * 64, j0 = jt * 64;
    const int row = tid >> 2, c4 = (tid & 3) * 4;
    #pragma unroll
    for (int p = 0; p < 4; ++p) {
        int dd = c4 + p * 16;
        float4 a = *(const float4*)&A[(size_t)(i0 + row) * DMODEL + h * HD + dd];
        Atile[dd + 0][row] = a.x; Atile[dd + 1][row] = a.y;
        Atile[dd + 2][row] = a.z; Atile[dd + 3][row] = a.w;
        float4 b = *(const float4*)&B[(size_t)(j0 + row) * DMODEL + h * HD + dd];
        Btile[dd + 0][row] = b.x; Btile[dd + 1][row] = b.y;
        Btile[dd + 2][row] = b.z; Btile[dd + 3][row] = b.w;
    }
    __syncthreads();
    float acc[4][4] = {};
    #pragma unroll 8
    for (int kk = 0; kk < 64; ++kk) {
        float4 a4 = *(const float4*)&Atile[kk][ty * 4];
        float4 b4 = *(const float4*)&Btile[kk][tx * 4];
        float av[4] = {a4.x, a4.y, a4.z, a4.w};
        float bv[4] = {b4.x, b4.y, b4.z, b4.w};
        #pragma unroll
        for (int m = 0; m < 4; ++m)
            #pragma unroll
            for (int n = 0; n < 4; ++n)
                acc[m][n] = fmaf(av[m], bv[n], acc[m][n]);
    }
    float* Ch = C + (size_t)hh * TSEQ * TSEQ;
    #pragma unroll
    for (int m = 0; m < 4; ++m) {
        int i = i0 + ty * 4 + m;
        float sc = (mode == 1) ? beta[i * NH + h] : 1.f;
        float v[4];
        #pragma unroll
        for (int n = 0; n < 4; ++n) {
            int j = j0 + tx * 4 + n;
            bool keep = mode ? (i > j) : (i >= j);
            v[n] = keep ? acc[m][n] * sc : 0.f;
        }
        float4 o = {v[0], v[1], v[2], v[3]};
        *(float4*)&Ch[(size_t)i * TSEQ + j0 + tx * 4] = o;
    }
}

// ---------------- blocked triangular solve step for column-chunk c ----------------
// Solves G (I+M) = QW in place (G buffer initially holds causal-masked QW).
// Chunks processed c = 15 .. 0 by successive launches.
// Phase A: acc = sum_{c'=c+1..rt} G[rows, c'] @ M[c', c]   (dense 64^3 tile GEMMs)
// Phase B: backward substitution vs unit-lower diag block M[c,c] (one row per wave).
__global__ __launch_bounds__(256) void solve_chunk(float* __restrict__ G,
    const float* __restrict__ Mm, int c)
{
    const int rt = c + blockIdx.x;       // row tile in [c, 15]
    const int hh = blockIdx.y;
    float* Gh = G + (size_t)hh * TSEQ * TSEQ;
    const float* Mh = Mm + (size_t)hh * TSEQ * TSEQ;
    __shared__ float T0[64][68];         // phase A: G^T [s][i]; phase B: RHS [i][j]
    __shared__ float T1[64][68];         // M [s][j]; phase B: Mcc [s][j]
    const int tid = threadIdx.x, tx = tid & 15, ty = tid >> 4;
    const int i0 = rt * 64, j0 = c * 64;
    const int row = tid >> 2, c4 = (tid & 3) * 4;
    float acc[4][4] = {};
    for (int cp = c + 1; cp <= rt; ++cp) {
        const int s0 = cp * 64;
        #pragma unroll
        for (int p = 0; p < 4; ++p) {
            int dd = c4 + p * 16;
            float4 g = *(const float4*)&Gh[(size_t)(i0 + row) * TSEQ + s0 + dd];
            T0[dd + 0][row] = g.x; T0[dd + 1][row] = g.y;
            T0[dd + 2][row] = g.z; T0[dd + 3][row] = g.w;
            *(float4*)&T1[row][dd] = *(const float4*)&Mh[(size_t)(s0 + row) * TSEQ + j0 + dd];
        }
        __syncthreads();
        #pragma unroll 8
        for (int kk = 0; kk < 64; ++kk) {
            float4 a4 = *(const float4*)&T0[kk][ty * 4];
            float4 b4 = *(const float4*)&T1[kk][tx * 4];
            float av[4] = {a4.x, a4.y, a4.z, a4.w};
            float bv[4] = {b4.x, b4.y, b4.z, b4.w};
            #pragma unroll
            for (int m = 0; m < 4; ++m)
                #pragma unroll
                for (int n = 0; n < 4; ++n)
                    acc[m][n] = fmaf(av[m], bv[n], acc[m][n]);
        }
        __syncthreads();
    }
    // RHS = current(QW) - acc  -> T0 as [i][j]
    #pragma unroll
    for (int m = 0; m < 4; ++m)
        #pragma unroll
        for (int n = 0; n < 4; ++n)
            T0[ty * 4 + m][tx * 4 + n] =
                Gh[(size_t)(i0 + ty * 4 + m) * TSEQ + j0 + tx * 4 + n] - acc[m][n];
    // Mcc (unit-diag block, strict-lower values, zeros elsewhere)
    #pragma unroll
    for (int p = 0; p < 4; ++p) {
        int dd = c4 + p * 16;
        *(float4*)&T1[row][dd] = *(const float4*)&Mh[(size_t)(j0 + row) * TSEQ + j0 + dd];
    }
    __syncthreads();
    // per-row backward substitution: G[i][s] = RHS[i][s] - sum_{s'>s} G[i][s'] Mcc[s'][s]
    const int wv = tid >> 6, lane = tid & 63;
    for (int qr = 0; qr < 16; ++qr) {
        const int r_ = wv * 16 + qr;
        float rv = T0[r_][lane];
        for (int s = 63; s >= 1; --s) {
            float g = __shfl(rv, s, 64);
            if (lane < s) rv = fmaf(-g, T1[s][lane], rv);
        }
        Gh[(size_t)(i0 + r_) * TSEQ + j0 + lane] = rv;
    }
}

// ---------------- S -= G @ Mk  (triangular-tile GEMM) ----------------
__global__ __launch_bounds__(256) void s_update(float* __restrict__ S,
    const float* __restrict__ G, const float* __restrict__ Mk)
{
    const int jt = blockIdx.x, it = blockIdx.y, hh = blockIdx.z;
    if (jt > it) return;
    const float* Gh = G + (size_t)hh * TSEQ * TSEQ;
    const float* Mh = Mk + (size_t)hh * TSEQ * TSEQ;
    float* Sh = S + (size_t)hh * TSEQ * TSEQ;
    __shared__ float Gt[64][68];  // [s][i]
    __shared__ float Ms[64][68];  // [s][j]
    const int tid = threadIdx.x, tx = tid & 15, ty = tid >> 4;
    const int i0 = it * 64, j0 = jt * 64;
    const int row = tid >> 2, c4 = (tid & 3) * 4;
    float acc[4][4] = {};
    for (int st = jt; st <= it; ++st) {   // stored zeros handle s<=j and s>i edges
        const int s0 = st * 64;
        #pragma unroll
        for (int p = 0; p < 4; ++p) {
            int dd = c4 + p * 16;
            float4 g = *(const float4*)&Gh[(size_t)(i0 + row) * TSEQ + s0 + dd];
            Gt[dd + 0][row] = g.x; Gt[dd + 1][row] = g.y;
            Gt[dd + 2][row] = g.z; Gt[dd + 3][row] = g.w;
            *(float4*)&Ms[row][dd] = *(const float4*)&Mh[(size_t)(s0 + row) * TSEQ + j0 + dd];
        }
        __syncthreads();
        #pragma unroll 8
        for (int kk = 0; kk < 64; ++kk) {
            float4 a4 = *(const float4*)&Gt[kk][ty * 4];
            float4 b4 = *(const float4*)&Ms[kk][tx * 4];
            float av[4] = {a4.x, a4.y, a4.z, a4.w};
            float bv[4] = {b4.x, b4.y, b4.z, b4.w};
            #pragma unroll
            for (int m = 0; m < 4; ++m)
                #pragma unroll
                for (int n = 0; n < 4; ++n)
                    acc[m][n] = fmaf(av[m], bv[n], acc[m][n]);
        }
        __syncthreads();
    }
    #pragma unroll
    for (int m = 0; m < 4; ++m) {
        float* p = &Sh[(size_t)(i0 + ty * 4 + m) * TSEQ + j0 + tx * 4];
        float4 sv = *(float4*)p;
        sv.x -= acc[m][0]; sv.y -= acc[m][1]; sv.z -= acc[m][2]; sv.w -= acc[m][3];
        *(float4*)p = sv;
    }
}

// ---------------- causal row softmax with D^-0.5 scaling, in place ----------------
__global__ __launch_bounds__(256) void softmax_causal(float* __restrict__ S)
{
    const int i = blockIdx.x, hh = blockIdx.y;
    float* row = S + (size_t)hh * TSEQ * TSEQ + (size_t)i * TSEQ;
    const int tid = threadIdx.x;
    const float sc = 0.125f;  // 64^-0.5
    __shared__ float red[256];
    float mx = -3.4e38f;
    for (int j = tid; j <= i; j += 256) mx = fmaxf(mx, row[j] * sc);
    red[tid] = mx; __syncthreads();
    for (int off = 128; off >= 1; off >>= 1) {
        if (tid < off) red[tid] = fmaxf(red[tid], red[tid + off]);
        __syncthreads();
    }
    mx = red[0]; __syncthreads();
    float sum = 0.f;
    for (int j = tid; j <= i; j += 256) {
        float e = expf(row[j] * sc - mx);
        row[j] = e; sum += e;
    }
    red[tid] = sum; __syncthreads();
    for (int off = 128; off >= 1; off >>= 1) {
        if (tid < off) red[tid] += red[tid + off];
        __syncthreads();
    }
    float inv = 1.f / red[0];
    for (int j = tid; j <= i; j += 256) row[j] *= inv;
}

// ---------------- O[head slice] = P @ V ----------------
__global__ __launch_bounds__(256) void pv64(const float* __restrict__ P,
    const float* __restrict__ V, float* __restrict__ O, int h0)
{
    const int it = blockIdx.x, hh = blockIdx.y, h = h0 + hh;
    const float* Ph = P + (size_t)hh * TSEQ * TSEQ;
    __shared__ float Pt[64][68];  // [j][i]
    __shared__ float Vs[64][68];  // [j][d]
    const int tid = threadIdx.x, tx = tid & 15, ty = tid >> 4;
    const int i0 = it * 64;
    const int row = tid >> 2, c4 = (tid & 3) * 4;
    float acc[4][4] = {};
    for (int jt = 0; jt <= it; ++jt) {
        const int j0 = jt * 64;
        const int i = i0 + row;
        #pragma unroll
        for (int p = 0; p < 4; ++p) {
            int dd = c4 + p * 16;
            float4 pv = *(const float4*)&Ph[(size_t)i * TSEQ + j0 + dd];
            Pt[dd + 0][row] = (j0 + dd + 0 <= i) ? pv.x : 0.f;
            Pt[dd + 1][row] = (j0 + dd + 1 <= i) ? pv.y : 0.f;
            Pt[dd + 2][row] = (j0 + dd + 2 <= i) ? pv.z : 0.f;
            Pt[dd + 3][row] = (j0 + dd + 3 <= i) ? pv.w : 0.f;
            *(float4*)&Vs[row][dd] = *(const float4*)&V[(size_t)(j0 + row) * DMODEL + h * HD + dd];
        }
        __syncthreads();
        #pragma unroll 8
        for (int kk = 0; kk < 64; ++kk) {
            float4 a4 = *(const float4*)&Pt[kk][ty * 4];
            float4 b4 = *(const float4*)&Vs[kk][tx * 4];
            float av[4] = {a4.x, a4.y, a4.z, a4.w};
            float bv[4] = {b4.x, b4.y, b4.z, b4.w};
            #pragma unroll
            for (int m = 0; m < 4; ++m)
                #pragma unroll
                for (int n = 0; n < 4; ++n)
                    acc[m][n] = fmaf(av[m], bv[n], acc[m][n]);
        }
        __syncthreads();
    }
    #pragma unroll
    for (int m = 0; m < 4; ++m) {
        float4 o = {acc[m][0], acc[m][1], acc[m][2], acc[m][3]};
        *(float4*)&O[(size_t)(i0 + ty * 4 + m) * DMODEL + h * HD + tx * 4] = o;
    }
}

extern "C" void kernel_launch(void* const* d_in, const int* in_sizes, int n_in,
                              void* d_out, int out_size, void* d_ws, size_t ws_size,
                              hipStream_t stream)
{
    const float* x   = (const float*)d_in[0];
    const float* Wq  = (const float*)d_in[1];
    const float* Wk  = (const float*)d_in[2];
    const float* Wv  = (const float*)d_in[3];
    const float* Ww1 = (const float*)d_in[4];
    const float* Ww2 = (const float*)d_in[5];
    const float* cw  = (const float*)d_in[6];
    const float* Wb  = (const float*)d_in[7];
    const float* Wo  = (const float*)d_in[8];
    float* out = (float*)d_out;

    float* ws = (float*)d_ws;
    size_t off = 0;
    auto alloc = [&](size_t n) { float* p = ws + off; off += n; return p; };
    float* q    = alloc((size_t)TSEQ * DMODEL);
    float* k    = alloc((size_t)TSEQ * DMODEL);
    float* v    = alloc((size_t)TSEQ * DMODEL);
    float* w    = alloc((size_t)TSEQ * DMODEL);
    float* wpre = alloc((size_t)TSEQ * DMODEL);
    float* oatt = alloc((size_t)TSEQ * DMODEL);
    float* xw1  = alloc((size_t)TSEQ * RANK);
    float* blog = alloc((size_t)TSEQ * NH);
    float* beta = alloc((size_t)TSEQ * NH);

    // Big per-head-group buffers: S, G(QW), M(->Mk). Pick largest head group
    // that fits ws_size (deterministic: ws_size is constant for the session).
    int HG = NH;
    while (HG > 1 && (off + 3ull * HG * TSEQ * TSEQ) * sizeof(float) > ws_size) HG >>= 1;
    float* Sb = alloc((size_t)HG * TSEQ * TSEQ);
    float* Gb = alloc((size_t)HG * TSEQ * TSEQ);
    float* Mb = alloc((size_t)HG * TSEQ * TSEQ);

    dim3 g64(DMODEL / 64, TSEQ / 64);
    gemm_f32<<<g64, 256, 0, stream>>>(x, Wq, q, TSEQ, DMODEL, DMODEL);
    gemm_f32<<<g64, 256, 0, stream>>>(x, Wk, k, TSEQ, DMODEL, DMODEL);
    gemm_f32<<<g64, 256, 0, stream>>>(x, Wv, v, TSEQ, DMODEL, DMODEL);
    gemm_skinny_rows<<<TSEQ, 256, 0, stream>>>(x, Ww1, xw1, RANK, DMODEL);
    gemm_f32<<<g64, 256, 0, stream>>>(xw1, Ww2, wpre, TSEQ, DMODEL, RANK);
    gemm_skinny_rows<<<TSEQ, 256, 0, stream>>>(x, Wb, blog, NH, DMODEL);
    conv_silu_norm<<<dim3(TSEQ, NH), 64, 0, stream>>>(wpre, cw, blog, w, beta);

    for (int h0 = 0; h0 < NH; h0 += HG) {
        dim3 gp(16, 16, HG);
        pairwise64<<<gp, 256, 0, stream>>>(w, w, beta, Mb, 1, h0);      // M  (strict, beta)
        pairwise64<<<gp, 256, 0, stream>>>(q, w, nullptr, Gb, 0, h0);   // QW (causal) -> RHS
        pairwise64<<<gp, 256, 0, stream>>>(q, k, nullptr, Sb, 0, h0);   // QK (causal)
        for (int c = 15; c >= 0; --c)
            solve_chunk<<<dim3(16 - c, HG), 256, 0, stream>>>(Gb, Mb, c);
        pairwise64<<<gp, 256, 0, stream>>>(w, k, beta, Mb, 1, h0);      // Mk (strict, beta), reuse M buf
        s_update<<<gp, 256, 0, stream>>>(Sb, Gb, Mb);                   // S = QK - G Mk
        softmax_causal<<<dim3(TSEQ, HG), 256, 0, stream>>>(Sb);
        pv64<<<dim3(16, HG), 256, 0, stream>>>(Sb, v, oatt, h0);
    }
    gemm_f32<<<g64, 256, 0, stream>>>(oatt, Wo, out, TSEQ, DMODEL, DMODEL);
}

// Round 5
// 1679.814 us; speedup vs baseline: 1.3010x; 1.0752x over previous
//
#include <hip/hip_runtime.h>
#include <math.h>

#define TSEQ 1024
#define DMODEL 1024
#define NH 16
#define HD 64
#define RANK 32

typedef __attribute__((ext_vector_type(8))) short bf16x8;
typedef __attribute__((ext_vector_type(4))) float f32x4;

// bf16 split helpers (RNE). hi = bf16(v); lo = bf16(v - hi). ~16 mantissa bits kept.
__device__ __forceinline__ unsigned short f2b(float f) {
    unsigned int u = __float_as_uint(f);
    u += 0x7fffu + ((u >> 16) & 1u);
    return (unsigned short)(u >> 16);
}
__device__ __forceinline__ float b2f(unsigned short h) {
    return __uint_as_float(((unsigned int)h) << 16);
}

// ---------------- split fp32 -> (hi, lo) bf16, row-major passthrough ----------------
__global__ __launch_bounds__(256) void split_rm(const float* __restrict__ S,
    unsigned short* __restrict__ Hi, unsigned short* __restrict__ Lo, int n4)
{
    int i = blockIdx.x * 256 + threadIdx.x;
    if (i >= n4) return;
    float4 v = *(const float4*)&S[(size_t)i * 4];
    float vv[4] = {v.x, v.y, v.z, v.w};
    unsigned int hw[2], lw[2];
    unsigned short h[4], l[4];
    #pragma unroll
    for (int p = 0; p < 4; ++p) {
        h[p] = f2b(vv[p]);
        l[p] = f2b(vv[p] - b2f(h[p]));
    }
    hw[0] = (unsigned int)h[0] | ((unsigned int)h[1] << 16);
    hw[1] = (unsigned int)h[2] | ((unsigned int)h[3] << 16);
    lw[0] = (unsigned int)l[0] | ((unsigned int)l[1] << 16);
    lw[1] = (unsigned int)l[2] | ((unsigned int)l[3] << 16);
    *(uint2*)&Hi[(size_t)i * 4] = make_uint2(hw[0], hw[1]);
    *(uint2*)&Lo[(size_t)i * 4] = make_uint2(lw[0], lw[1]);
}

// ---------------- split fp32 [K][N] -> transposed (hi, lo) bf16 [N][K] ----------------
__global__ __launch_bounds__(256) void split_tr(const float* __restrict__ S,
    unsigned short* __restrict__ Hi, unsigned short* __restrict__ Lo, int Kd, int Nd)
{
    __shared__ float T[64][65];
    const int i0 = blockIdx.y * 64;   // K rows
    const int j0 = blockIdx.x * 64;   // N cols
    const int tid = threadIdx.x;
    const int r = tid >> 2, c16 = (tid & 3) * 16;
    #pragma unroll
    for (int p = 0; p < 4; ++p) {
        float4 v = *(const float4*)&S[(size_t)(i0 + r) * Nd + j0 + c16 + p * 4];
        T[r][c16 + p * 4 + 0] = v.x; T[r][c16 + p * 4 + 1] = v.y;
        T[r][c16 + p * 4 + 2] = v.z; T[r][c16 + p * 4 + 3] = v.w;
    }
    __syncthreads();
    const int orow = tid & 63;        // output row = col j
    const int seg = tid >> 6;         // 16 K-values per thread
    unsigned short hb[16], lb[16];
    #pragma unroll
    for (int p = 0; p < 16; ++p) {
        float v = T[seg * 16 + p][orow];
        hb[p] = f2b(v);
        lb[p] = f2b(v - b2f(hb[p]));
    }
    size_t ob = (size_t)(j0 + orow) * Kd + i0 + seg * 16;
    unsigned int w[4];
    #pragma unroll
    for (int q = 0; q < 2; ++q) {
        #pragma unroll
        for (int p = 0; p < 4; ++p)
            w[p] = (unsigned int)hb[q*8 + 2*p] | ((unsigned int)hb[q*8 + 2*p + 1] << 16);
        *(uint4*)&Hi[ob + q * 8] = make_uint4(w[0], w[1], w[2], w[3]);
        #pragma unroll
        for (int p = 0; p < 4; ++p)
            w[p] = (unsigned int)lb[q*8 + 2*p] | ((unsigned int)lb[q*8 + 2*p + 1] << 16);
        *(uint4*)&Lo[ob + q * 8] = make_uint4(w[0], w[1], w[2], w[3]);
    }
}

// ---------------- split-bf16 MFMA GEMM: C[M,N] = A @ Bt^T ----------------
// A given as (Ahi+Alo) [M][K] bf16 pairs; B given transposed (Bthi+Btlo) [N][K].
// 3-term product AhiBhi + AloBhi + AhiBlo (fp32-grade, ~2^-16 rel err).
// grid (N/64, M/64), 256 threads = 4 waves; wave w -> rows [w*16, w*16+16) x 64 cols.
__global__ __launch_bounds__(256) void mfma_nt(
    const unsigned short* __restrict__ Ah_, const unsigned short* __restrict__ Al_, int lda,
    const unsigned short* __restrict__ Bh_, const unsigned short* __restrict__ Bl_, int ldb,
    float* __restrict__ C, int ldc, int K)
{
    __shared__ unsigned short Ah[64][72], Al[64][72], Bh[64][72], Bl[64][72];
    const int tid = threadIdx.x;
    const int i0 = blockIdx.y * 64, j0 = blockIdx.x * 64;
    const int srow = tid >> 2, sc = tid & 3;
    const int lane = tid & 63, wid = tid >> 6;
    const int lc = lane & 15, kg8 = (lane >> 4) * 8;
    f32x4 acc[4] = {{0.f,0.f,0.f,0.f},{0.f,0.f,0.f,0.f},{0.f,0.f,0.f,0.f},{0.f,0.f,0.f,0.f}};
    for (int k0 = 0; k0 < K; k0 += 64) {
        __syncthreads();
        const size_t ab = (size_t)(i0 + srow) * lda + k0;
        const size_t bb = (size_t)(j0 + srow) * ldb + k0;
        *(uint4*)&Ah[srow][sc * 8]       = *(const uint4*)&Ah_[ab + sc * 8];
        *(uint4*)&Ah[srow][(sc + 4) * 8] = *(const uint4*)&Ah_[ab + (sc + 4) * 8];
        *(uint4*)&Al[srow][sc * 8]       = *(const uint4*)&Al_[ab + sc * 8];
        *(uint4*)&Al[srow][(sc + 4) * 8] = *(const uint4*)&Al_[ab + (sc + 4) * 8];
        *(uint4*)&Bh[srow][sc * 8]       = *(const uint4*)&Bh_[bb + sc * 8];
        *(uint4*)&Bh[srow][(sc + 4) * 8] = *(const uint4*)&Bh_[bb + (sc + 4) * 8];
        *(uint4*)&Bl[srow][sc * 8]       = *(const uint4*)&Bl_[bb + sc * 8];
        *(uint4*)&Bl[srow][(sc + 4) * 8] = *(const uint4*)&Bl_[bb + (sc + 4) * 8];
        __syncthreads();
        #pragma unroll
        for (int ks = 0; ks < 2; ++ks) {
            bf16x8 a_h = *(const bf16x8*)&Ah[wid * 16 + lc][ks * 32 + kg8];
            bf16x8 a_l = *(const bf16x8*)&Al[wid * 16 + lc][ks * 32 + kg8];
            #pragma unroll
            for (int nt = 0; nt < 4; ++nt) {
                bf16x8 b_h = *(const bf16x8*)&Bh[nt * 16 + lc][ks * 32 + kg8];
                bf16x8 b_l = *(const bf16x8*)&Bl[nt * 16 + lc][ks * 32 + kg8];
                acc[nt] = __builtin_amdgcn_mfma_f32_16x16x32_bf16(a_h, b_h, acc[nt], 0, 0, 0);
                acc[nt] = __builtin_amdgcn_mfma_f32_16x16x32_bf16(a_l, b_h, acc[nt], 0, 0, 0);
                acc[nt] = __builtin_amdgcn_mfma_f32_16x16x32_bf16(a_h, b_l, acc[nt], 0, 0, 0);
            }
        }
    }
    const int orow = i0 + wid * 16 + (lane >> 4) * 4;
    #pragma unroll
    for (int nt = 0; nt < 4; ++nt)
        #pragma unroll
        for (int r = 0; r < 4; ++r)
            C[(size_t)(orow + r) * ldc + j0 + nt * 16 + lc] = acc[nt][r];
}

// ---------------- generic fp32 tiled GEMM (kept for K=32 wpre) ----------------
__global__ __launch_bounds__(256) void gemm_f32(const float* __restrict__ A,
    const float* __restrict__ B, float* __restrict__ C, int M, int N, int K)
{
    __shared__ float At[16][68];
    __shared__ float Bs[16][68];
    const int tid = threadIdx.x;
    const int tx = tid & 15, ty = tid >> 4;
    const int i0 = blockIdx.y * 64, j0 = blockIdx.x * 64;
    const int arow = tid >> 2, ac4 = (tid & 3) * 4;
    const int brow = tid >> 4, bc4 = (tid & 15) * 4;
    float acc[4][4] = {};
    for (int k0 = 0; k0 < K; k0 += 16) {
        float4 a = *(const float4*)&A[(size_t)(i0 + arow) * K + k0 + ac4];
        At[ac4 + 0][arow] = a.x; At[ac4 + 1][arow] = a.y;
        At[ac4 + 2][arow] = a.z; At[ac4 + 3][arow] = a.w;
        *(float4*)&Bs[brow][bc4] = *(const float4*)&B[(size_t)(k0 + brow) * N + j0 + bc4];
        __syncthreads();
        #pragma unroll
        for (int kk = 0; kk < 16; ++kk) {
            float4 a4 = *(const float4*)&At[kk][ty * 4];
            float4 b4 = *(const float4*)&Bs[kk][tx * 4];
            float av[4] = {a4.x, a4.y, a4.z, a4.w};
            float bv[4] = {b4.x, b4.y, b4.z, b4.w};
            #pragma unroll
            for (int m = 0; m < 4; ++m)
                #pragma unroll
                for (int n = 0; n < 4; ++n)
                    acc[m][n] = fmaf(av[m], bv[n], acc[m][n]);
        }
        __syncthreads();
    }
    #pragma unroll
    for (int m = 0; m < 4; ++m) {
        float4 o = {acc[m][0], acc[m][1], acc[m][2], acc[m][3]};
        *(float4*)&C[(size_t)(i0 + ty * 4 + m) * N + j0 + tx * 4] = o;
    }
}

// ---------------- skinny GEMM (N in {16,32}): row-parallel split-K ----------------
__global__ __launch_bounds__(256) void gemm_skinny_rows(const float* __restrict__ A,
    const float* __restrict__ B, float* __restrict__ C, int N, int K)
{
    const int row = blockIdx.x;
    const int tid = threadIdx.x;
    const int col = tid & (N - 1);
    const int ks = tid / N;
    const int nsl = 256 / N;
    const float* a = A + (size_t)row * K;
    float s = 0.f;
    for (int k = ks; k < K; k += nsl)
        s = fmaf(a[k], B[(size_t)k * N + col], s);
    __shared__ float red[256];
    red[tid] = s; __syncthreads();
    for (int off = 128; off >= N; off >>= 1) {
        if (tid < off) red[tid] += red[tid + off];
        __syncthreads();
    }
    if (tid < N) C[(size_t)row * N + col] = red[tid];
}

// ---------------- causal depthwise conv(3) + SiLU + per-head L2 norm + beta -------
__global__ __launch_bounds__(64) void conv_silu_norm(const float* __restrict__ wpre,
    const float* __restrict__ cw, const float* __restrict__ blog,
    float* __restrict__ w, float* __restrict__ beta)
{
    const int t = blockIdx.x, h = blockIdx.y, d = threadIdx.x;
    const int c = h * HD + d;
    float x2 = wpre[(size_t)t * DMODEL + c];
    float x1 = (t >= 1) ? wpre[(size_t)(t - 1) * DMODEL + c] : 0.f;
    float x0 = (t >= 2) ? wpre[(size_t)(t - 2) * DMODEL + c] : 0.f;
    float y = cw[c * 3 + 0] * x0 + cw[c * 3 + 1] * x1 + cw[c * 3 + 2] * x2;
    y = y / (1.f + expf(-y));
    float ss = y * y;
    #pragma unroll
    for (int off = 32; off >= 1; off >>= 1) ss += __shfl_xor(ss, off, 64);
    float r = 1.f / sqrtf(ss + 1e-6f);
    w[(size_t)t * DMODEL + c] = y * r;
    if (d == 0) beta[t * NH + h] = 2.f / (1.f + expf(-blog[t * NH + h]));
}

// ---------------- pairwise dots over head dim (K=64) ----------------
__global__ __launch_bounds__(256) void pairwise64(const float* __restrict__ A,
    const float* __restrict__ B, const float* __restrict__ beta,
    float* __restrict__ C, int mode, int h0)
{
    const int jt = blockIdx.x, it = blockIdx.y, hh = blockIdx.z;
    if (jt > it) return;
    const int h = h0 + hh;
    __shared__ float Atile[64][68];
    __shared__ float Btile[64][68];
    const int tid = threadIdx.x;
    const int tx = tid & 15, ty = tid >> 4;
    const int i0 = it * 64, j0 = jt * 64;
    const int row = tid >> 2, c4 = (tid & 3) * 4;
    #pragma unroll
    for (int p = 0; p < 4; ++p) {
        int dd = c4 + p * 16;
        float4 a = *(const float4*)&A[(size_t)(i0 + row) * DMODEL + h * HD + dd];
        Atile[dd + 0][row] = a.x; Atile[dd + 1][row] = a.y;
        Atile[dd + 2][row] = a.z; Atile[dd + 3][row] = a.w;
        float4 b = *(const float4*)&B[(size_t)(j0 + row) * DMODEL + h * HD + dd];
        Btile[dd + 0][row] = b.x; Btile[dd + 1][row] = b.y;
        Btile[dd + 2][row] = b.z; Btile[dd + 3][row] = b.w;
    }
    __syncthreads();
    float acc[4][4] = {};
    #pragma unroll 8
    for (int kk = 0; kk < 64; ++kk) {
        float4 a4 = *(const float4*)&Atile[kk][ty * 4];
        float4 b4 = *(const float4*)&Btile[kk][tx * 4];
        float av[4] = {a4.x, a4.y, a4.z, a4.w};
        float bv[4] = {b4.x, b4.y, b4.z, b4.w};
        #pragma unroll
        for (int m = 0; m < 4; ++m)
            #pragma unroll
            for (int n = 0; n < 4; ++n)
                acc[m][n] = fmaf(av[m], bv[n], acc[m][n]);
    }
    float* Ch = C + (size_t)hh * TSEQ * TSEQ;
    #pragma unroll
    for (int m = 0; m < 4; ++m) {
        int i = i0 + ty * 4 + m;
        float sc = (mode == 1) ? beta[i * NH + h] : 1.f;
        float v[4];
        #pragma unroll
        for (int n = 0; n < 4; ++n) {
            int j = j0 + tx * 4 + n;
            bool keep = mode ? (i > j) : (i >= j);
            v[n] = keep ? acc[m][n] * sc : 0.f;
        }
        float4 o = {v[0], v[1], v[2], v[3]};
        *(float4*)&Ch[(size_t)i * TSEQ + j0 + tx * 4] = o;
    }
}

// ---------------- blocked triangular solve step for column-chunk c ----------------
__global__ __launch_bounds__(256) void solve_chunk(float* __restrict__ G,
    const float* __restrict__ Mm, int c)
{
    const int rt = c + blockIdx.x;
    const int hh = blockIdx.y;
    float* Gh = G + (size_t)hh * TSEQ * TSEQ;
    const float* Mh = Mm + (size_t)hh * TSEQ * TSEQ;
    __shared__ float T0[64][68];
    __shared__ float T1[64][68];
    const int tid = threadIdx.x, tx = tid & 15, ty = tid >> 4;
    const int i0 = rt * 64, j0 = c * 64;
    const int row = tid >> 2, c4 = (tid & 3) * 4;
    float acc[4][4] = {};
    for (int cp = c + 1; cp <= rt; ++cp) {
        const int s0 = cp * 64;
        #pragma unroll
        for (int p = 0; p < 4; ++p) {
            int dd = c4 + p * 16;
            float4 g = *(const float4*)&Gh[(size_t)(i0 + row) * TSEQ + s0 + dd];
            T0[dd + 0][row] = g.x; T0[dd + 1][row] = g.y;
            T0[dd + 2][row] = g.z; T0[dd + 3][row] = g.w;
            *(float4*)&T1[row][dd] = *(const float4*)&Mh[(size_t)(s0 + row) * TSEQ + j0 + dd];
        }
        __syncthreads();
        #pragma unroll 8
        for (int kk = 0; kk < 64; ++kk) {
            float4 a4 = *(const float4*)&T0[kk][ty * 4];
            float4 b4 = *(const float4*)&T1[kk][tx * 4];
            float av[4] = {a4.x, a4.y, a4.z, a4.w};
            float bv[4] = {b4.x, b4.y, b4.z, b4.w};
            #pragma unroll
            for (int m = 0; m < 4; ++m)
                #pragma unroll
                for (int n = 0; n < 4; ++n)
                    acc[m][n] = fmaf(av[m], bv[n], acc[m][n]);
        }
        __syncthreads();
    }
    #pragma unroll
    for (int m = 0; m < 4; ++m)
        #pragma unroll
        for (int n = 0; n < 4; ++n)
            T0[ty * 4 + m][tx * 4 + n] =
                Gh[(size_t)(i0 + ty * 4 + m) * TSEQ + j0 + tx * 4 + n] - acc[m][n];
    #pragma unroll
    for (int p = 0; p < 4; ++p) {
        int dd = c4 + p * 16;
        *(float4*)&T1[row][dd] = *(const float4*)&Mh[(size_t)(j0 + row) * TSEQ + j0 + dd];
    }
    __syncthreads();
    const int wv = tid >> 6, lane = tid & 63;
    for (int qr = 0; qr < 16; ++qr) {
        const int r_ = wv * 16 + qr;
        float rv = T0[r_][lane];
        for (int s = 63; s >= 1; --s) {
            float g = __shfl(rv, s, 64);
            if (lane < s) rv = fmaf(-g, T1[s][lane], rv);
        }
        Gh[(size_t)(i0 + r_) * TSEQ + j0 + lane] = rv;
    }
}

// ---------------- S -= G @ Mk (triangular-tile GEMM, fp32) ----------------
__global__ __launch_bounds__(256) void s_update(float* __restrict__ S,
    const float* __restrict__ G, const float* __restrict__ Mk)
{
    const int jt = blockIdx.x, it = blockIdx.y, hh = blockIdx.z;
    if (jt > it) return;
    const float* Gh = G + (size_t)hh * TSEQ * TSEQ;
    const float* Mh = Mk + (size_t)hh * TSEQ * TSEQ;
    float* Sh = S + (size_t)hh * TSEQ * TSEQ;
    __shared__ float Gt[64][68];
    __shared__ float Ms[64][68];
    const int tid = threadIdx.x, tx = tid & 15, ty = tid >> 4;
    const int i0 = it * 64, j0 = jt * 64;
    const int row = tid >> 2, c4 = (tid & 3) * 4;
    float acc[4][4] = {};
    for (int st = jt; st <= it; ++st) {
        const int s0 = st * 64;
        #pragma unroll
        for (int p = 0; p < 4; ++p) {
            int dd = c4 + p * 16;
            float4 g = *(const float4*)&Gh[(size_t)(i0 + row) * TSEQ + s0 + dd];
            Gt[dd + 0][row] = g.x; Gt[dd + 1][row] = g.y;
            Gt[dd + 2][row] = g.z; Gt[dd + 3][row] = g.w;
            *(float4*)&Ms[row][dd] = *(const float4*)&Mh[(size_t)(s0 + row) * TSEQ + j0 + dd];
        }
        __syncthreads();
        #pragma unroll 8
        for (int kk = 0; kk < 64; ++kk) {
            float4 a4 = *(const float4*)&Gt[kk][ty * 4];
            float4 b4 = *(const float4*)&Ms[kk][tx * 4];
            float av[4] = {a4.x, a4.y, a4.z, a4.w};
            float bv[4] = {b4.x, b4.y, b4.z, b4.w};
            #pragma unroll
            for (int m = 0; m < 4; ++m)
                #pragma unroll
                for (int n = 0; n < 4; ++n)
                    acc[m][n] = fmaf(av[m], bv[n], acc[m][n]);
        }
        __syncthreads();
    }
    #pragma unroll
    for (int m = 0; m < 4; ++m) {
        float* p = &Sh[(size_t)(i0 + ty * 4 + m) * TSEQ + j0 + tx * 4];
        float4 sv = *(float4*)p;
        sv.x -= acc[m][0]; sv.y -= acc[m][1]; sv.z -= acc[m][2]; sv.w -= acc[m][3];
        *(float4*)p = sv;
    }
}

// ---------------- causal row softmax with D^-0.5 scaling, in place ----------------
__global__ __launch_bounds__(256) void softmax_causal(float* __restrict__ S)
{
    const int i = blockIdx.x, hh = blockIdx.y;
    float* row = S + (size_t)hh * TSEQ * TSEQ + (size_t)i * TSEQ;
    const int tid = threadIdx.x;
    const float sc = 0.125f;
    __shared__ float red[256];
    float mx = -3.4e38f;
    for (int j = tid; j <= i; j += 256) mx = fmaxf(mx, row[j] * sc);
    red[tid] = mx; __syncthreads();
    for (int off = 128; off >= 1; off >>= 1) {
        if (tid < off) red[tid] = fmaxf(red[tid], red[tid + off]);
        __syncthreads();
    }
    mx = red[0]; __syncthreads();
    float sum = 0.f;
    for (int j = tid; j <= i; j += 256) {
        float e = expf(row[j] * sc - mx);
        row[j] = e; sum += e;
    }
    red[tid] = sum; __syncthreads();
    for (int off = 128; off >= 1; off >>= 1) {
        if (tid < off) red[tid] += red[tid + off];
        __syncthreads();
    }
    float inv = 1.f / red[0];
    for (int j = tid; j <= i; j += 256) row[j] *= inv;
}

// ---------------- O[head slice] = P @ V ----------------
__global__ __launch_bounds__(256) void pv64(const float* __restrict__ P,
    const float* __restrict__ V, float* __restrict__ O, int h0)
{
    const int it = blockIdx.x, hh = blockIdx.y, h = h0 + hh;
    const float* Ph = P + (size_t)hh * TSEQ * TSEQ;
    __shared__ float Pt[64][68];
    __shared__ float Vs[64][68];
    const int tid = threadIdx.x, tx = tid & 15, ty = tid >> 4;
    const int i0 = it * 64;
    const int row = tid >> 2, c4 = (tid & 3) * 4;
    float acc[4][4] = {};
    for (int jt = 0; jt <= it; ++jt) {
        const int j0 = jt * 64;
        const int i = i0 + row;
        #pragma unroll
        for (int p = 0; p < 4; ++p) {
            int dd = c4 + p * 16;
            float4 pv = *(const float4*)&Ph[(size_t)i * TSEQ + j0 + dd];
            Pt[dd + 0][row] = (j0 + dd + 0 <= i) ? pv.x : 0.f;
            Pt[dd + 1][row] = (j0 + dd + 1 <= i) ? pv.y : 0.f;
            Pt[dd + 2][row] = (j0 + dd + 2 <= i) ? pv.z : 0.f;
            Pt[dd + 3][row] = (j0 + dd + 3 <= i) ? pv.w : 0.f;
            *(float4*)&Vs[row][dd] = *(const float4*)&V[(size_t)(j0 + row) * DMODEL + h * HD + dd];
        }
        __syncthreads();
        #pragma unroll 8
        for (int kk = 0; kk < 64; ++kk) {
            float4 a4 = *(const float4*)&Pt[kk][ty * 4];
            float4 b4 = *(const float4*)&Vs[kk][tx * 4];
            float av[4] = {a4.x, a4.y, a4.z, a4.w};
            float bv[4] = {b4.x, b4.y, b4.z, b4.w};
            #pragma unroll
            for (int m = 0; m < 4; ++m)
                #pragma unroll
                for (int n = 0; n < 4; ++n)
                    acc[m][n] = fmaf(av[m], bv[n], acc[m][n]);
        }
        __syncthreads();
    }
    #pragma unroll
    for (int m = 0; m < 4; ++m) {
        float4 o = {acc[m][0], acc[m][1], acc[m][2], acc[m][3]};
        *(float4*)&O[(size_t)(i0 + ty * 4 + m) * DMODEL + h * HD + tx * 4] = o;
    }
}

extern "C" void kernel_launch(void* const* d_in, const int* in_sizes, int n_in,
                              void* d_out, int out_size, void* d_ws, size_t ws_size,
                              hipStream_t stream)
{
    const float* x   = (const float*)d_in[0];
    const float* Wq  = (const float*)d_in[1];
    const float* Wk  = (const float*)d_in[2];
    const float* Wv  = (const float*)d_in[3];
    const float* Ww1 = (const float*)d_in[4];
    const float* Ww2 = (const float*)d_in[5];
    const float* cw  = (const float*)d_in[6];
    const float* Wb  = (const float*)d_in[7];
    const float* Wo  = (const float*)d_in[8];
    float* out = (float*)d_out;

    float* ws = (float*)d_ws;
    size_t off = 0;
    auto alloc = [&](size_t n) { float* p = ws + off; off += n; return p; };
    float* q    = alloc((size_t)TSEQ * DMODEL);
    float* k    = alloc((size_t)TSEQ * DMODEL);
    float* v    = alloc((size_t)TSEQ * DMODEL);
    float* w    = alloc((size_t)TSEQ * DMODEL);
    float* wpre = alloc((size_t)TSEQ * DMODEL);
    float* oatt = alloc((size_t)TSEQ * DMODEL);
    float* xw1  = alloc((size_t)TSEQ * RANK);
    float* blog = alloc((size_t)TSEQ * NH);
    float* beta = alloc((size_t)TSEQ * NH);

    // Big region: trio (S, G, M) during the loop; split buffers are OVERLAID on it
    // pre-loop (x + Wq/Wk/Wv splits, 16MB) and post-loop (oatt + Wo splits, 8MB),
    // which are time-disjoint with the trio -> no additional peak memory.
    int HG = NH;
    while (HG > 1 && (off + 3ull * HG * TSEQ * TSEQ) * sizeof(float) > ws_size) HG >>= 1;
    float* big = ws + off;
    float* Sb = big;
    float* Gb = big + (size_t)HG * TSEQ * TSEQ;
    float* Mb = big + 2ull * HG * TSEQ * TSEQ;

    const size_t E = (size_t)TSEQ * DMODEL;     // 1M elements
    unsigned short* us = (unsigned short*)big;
    unsigned short* xs_h  = us;          unsigned short* xs_l  = us + E;
    unsigned short* wqt_h = us + 2 * E;  unsigned short* wqt_l = us + 3 * E;
    unsigned short* wkt_h = us + 4 * E;  unsigned short* wkt_l = us + 5 * E;
    unsigned short* wvt_h = us + 6 * E;  unsigned short* wvt_l = us + 7 * E;
    // post-loop overlays (same region, reused after trio is dead)
    unsigned short* oat_h = us;          unsigned short* oat_l = us + E;
    unsigned short* wot_h = us + 2 * E;  unsigned short* wot_l = us + 3 * E;

    dim3 g64(DMODEL / 64, TSEQ / 64);
    dim3 gt(16, 16);

    // --- projections via split-bf16 MFMA ---
    split_rm<<<(int)(E / 4 + 255) / 256, 256, 0, stream>>>(x, xs_h, xs_l, (int)(E / 4));
    split_tr<<<gt, 256, 0, stream>>>(Wq, wqt_h, wqt_l, DMODEL, DMODEL);
    split_tr<<<gt, 256, 0, stream>>>(Wk, wkt_h, wkt_l, DMODEL, DMODEL);
    split_tr<<<gt, 256, 0, stream>>>(Wv, wvt_h, wvt_l, DMODEL, DMODEL);
    mfma_nt<<<g64, 256, 0, stream>>>(xs_h, xs_l, DMODEL, wqt_h, wqt_l, DMODEL, q, DMODEL, DMODEL);
    mfma_nt<<<g64, 256, 0, stream>>>(xs_h, xs_l, DMODEL, wkt_h, wkt_l, DMODEL, k, DMODEL, DMODEL);
    mfma_nt<<<g64, 256, 0, stream>>>(xs_h, xs_l, DMODEL, wvt_h, wvt_l, DMODEL, v, DMODEL, DMODEL);
    gemm_skinny_rows<<<TSEQ, 256, 0, stream>>>(x, Ww1, xw1, RANK, DMODEL);
    gemm_f32<<<g64, 256, 0, stream>>>(xw1, Ww2, wpre, TSEQ, DMODEL, RANK);
    gemm_skinny_rows<<<TSEQ, 256, 0, stream>>>(x, Wb, blog, NH, DMODEL);
    conv_silu_norm<<<dim3(TSEQ, NH), 64, 0, stream>>>(wpre, cw, blog, w, beta);

    for (int h0 = 0; h0 < NH; h0 += HG) {
        dim3 gp(16, 16, HG);
        pairwise64<<<gp, 256, 0, stream>>>(w, w, beta, Mb, 1, h0);      // M  (strict, beta)
        pairwise64<<<gp, 256, 0, stream>>>(q, w, nullptr, Gb, 0, h0);   // QW (causal) -> RHS
        pairwise64<<<gp, 256, 0, stream>>>(q, k, nullptr, Sb, 0, h0);   // QK (causal)
        for (int c = 15; c >= 0; --c)
            solve_chunk<<<dim3(16 - c, HG), 256, 0, stream>>>(Gb, Mb, c);
        pairwise64<<<gp, 256, 0, stream>>>(w, k, beta, Mb, 1, h0);      // Mk (strict, beta)
        s_update<<<gp, 256, 0, stream>>>(Sb, Gb, Mb);                   // S = QK - G Mk
        softmax_causal<<<dim3(TSEQ, HG), 256, 0, stream>>>(Sb);
        pv64<<<dim3(16, HG), 256, 0, stream>>>(Sb, v, oatt, h0);
    }

    // --- final projection via split-bf16 MFMA (overlays trio region, now dead) ---
    split_rm<<<(int)(E / 4 + 255) / 256, 256, 0, stream>>>(oatt, oat_h, oat_l, (int)(E / 4));
    split_tr<<<gt, 256, 0, stream>>>(Wo, wot_h, wot_l, DMODEL, DMODEL);
    mfma_nt<<<g64, 256, 0, stream>>>(oat_h, oat_l, DMODEL, wot_h, wot_l, DMODEL, out, DMODEL, DMODEL);
}

// Round 7
// 1546.122 us; speedup vs baseline: 1.4135x; 1.0865x over previous
//
#include <hip/hip_runtime.h>
#include <math.h>

#define TSEQ 1024
#define DMODEL 1024
#define NH 16
#define HD 64
#define RANK 32

typedef __attribute__((ext_vector_type(8))) short bf16x8;
typedef __attribute__((ext_vector_type(4))) float f32x4;

// bf16 split helpers (RNE). hi = bf16(v); lo = bf16(v - hi). ~16 mantissa bits kept.
__device__ __forceinline__ unsigned short f2b(float f) {
    unsigned int u = __float_as_uint(f);
    u += 0x7fffu + ((u >> 16) & 1u);
    return (unsigned short)(u >> 16);
}
__device__ __forceinline__ float b2f(unsigned short h) {
    return __uint_as_float(((unsigned int)h) << 16);
}
__device__ __forceinline__ void split2(float v, unsigned short& h, unsigned short& l) {
    h = f2b(v); l = f2b(v - b2f(h));
}

// ---------------- split fp32 -> (hi, lo) bf16, row-major passthrough ----------------
__global__ __launch_bounds__(256) void split_rm(const float* __restrict__ S,
    unsigned short* __restrict__ Hi, unsigned short* __restrict__ Lo, int n4)
{
    int i = blockIdx.x * 256 + threadIdx.x;
    if (i >= n4) return;
    float4 v = *(const float4*)&S[(size_t)i * 4];
    float vv[4] = {v.x, v.y, v.z, v.w};
    unsigned int hw[2], lw[2];
    unsigned short h[4], l[4];
    #pragma unroll
    for (int p = 0; p < 4; ++p) split2(vv[p], h[p], l[p]);
    hw[0] = (unsigned int)h[0] | ((unsigned int)h[1] << 16);
    hw[1] = (unsigned int)h[2] | ((unsigned int)h[3] << 16);
    lw[0] = (unsigned int)l[0] | ((unsigned int)l[1] << 16);
    lw[1] = (unsigned int)l[2] | ((unsigned int)l[3] << 16);
    *(uint2*)&Hi[(size_t)i * 4] = make_uint2(hw[0], hw[1]);
    *(uint2*)&Lo[(size_t)i * 4] = make_uint2(lw[0], lw[1]);
}

// ---------------- split fp32 [K][N] -> transposed (hi, lo) bf16 [N][K] ----------------
__global__ __launch_bounds__(256) void split_tr(const float* __restrict__ S,
    unsigned short* __restrict__ Hi, unsigned short* __restrict__ Lo, int Kd, int Nd)
{
    __shared__ float T[64][65];
    const int i0 = blockIdx.y * 64;   // K rows
    const int j0 = blockIdx.x * 64;   // N cols
    const int tid = threadIdx.x;
    const int r = tid >> 2, c16 = (tid & 3) * 16;
    #pragma unroll
    for (int p = 0; p < 4; ++p) {
        float4 v = *(const float4*)&S[(size_t)(i0 + r) * Nd + j0 + c16 + p * 4];
        T[r][c16 + p * 4 + 0] = v.x; T[r][c16 + p * 4 + 1] = v.y;
        T[r][c16 + p * 4 + 2] = v.z; T[r][c16 + p * 4 + 3] = v.w;
    }
    __syncthreads();
    const int orow = tid & 63;        // output row = col j
    const int seg = tid >> 6;         // 16 K-values per thread
    unsigned short hb[16], lb[16];
    #pragma unroll
    for (int p = 0; p < 16; ++p) split2(T[seg * 16 + p][orow], hb[p], lb[p]);
    size_t ob = (size_t)(j0 + orow) * Kd + i0 + seg * 16;
    unsigned int w[4];
    #pragma unroll
    for (int q = 0; q < 2; ++q) {
        #pragma unroll
        for (int p = 0; p < 4; ++p)
            w[p] = (unsigned int)hb[q*8 + 2*p] | ((unsigned int)hb[q*8 + 2*p + 1] << 16);
        *(uint4*)&Hi[ob + q * 8] = make_uint4(w[0], w[1], w[2], w[3]);
        #pragma unroll
        for (int p = 0; p < 4; ++p)
            w[p] = (unsigned int)lb[q*8 + 2*p] | ((unsigned int)lb[q*8 + 2*p + 1] << 16);
        *(uint4*)&Lo[ob + q * 8] = make_uint4(w[0], w[1], w[2], w[3]);
    }
}

// ---------------- split-bf16 MFMA GEMM: C[M,N] = A @ Bt^T ----------------
// A as (hi,lo) [M][K]; B transposed (hi,lo) [N][K]. 3-term AhBh + AlBh + AhBl.
__global__ __launch_bounds__(256) void mfma_nt(
    const unsigned short* __restrict__ Ah_, const unsigned short* __restrict__ Al_, int lda,
    const unsigned short* __restrict__ Bh_, const unsigned short* __restrict__ Bl_, int ldb,
    float* __restrict__ C, int ldc, int K)
{
    __shared__ unsigned short Ah[64][72], Al[64][72], Bh[64][72], Bl[64][72];
    const int tid = threadIdx.x;
    const int i0 = blockIdx.y * 64, j0 = blockIdx.x * 64;
    const int srow = tid >> 2, sc = tid & 3;
    const int lane = tid & 63, wid = tid >> 6;
    const int lc = lane & 15, kg8 = (lane >> 4) * 8;
    f32x4 acc[4] = {{0.f,0.f,0.f,0.f},{0.f,0.f,0.f,0.f},{0.f,0.f,0.f,0.f},{0.f,0.f,0.f,0.f}};
    for (int k0 = 0; k0 < K; k0 += 64) {
        __syncthreads();
        const size_t ab = (size_t)(i0 + srow) * lda + k0;
        const size_t bb = (size_t)(j0 + srow) * ldb + k0;
        *(uint4*)&Ah[srow][sc * 8]       = *(const uint4*)&Ah_[ab + sc * 8];
        *(uint4*)&Ah[srow][(sc + 4) * 8] = *(const uint4*)&Ah_[ab + (sc + 4) * 8];
        *(uint4*)&Al[srow][sc * 8]       = *(const uint4*)&Al_[ab + sc * 8];
        *(uint4*)&Al[srow][(sc + 4) * 8] = *(const uint4*)&Al_[ab + (sc + 4) * 8];
        *(uint4*)&Bh[srow][sc * 8]       = *(const uint4*)&Bh_[bb + sc * 8];
        *(uint4*)&Bh[srow][(sc + 4) * 8] = *(const uint4*)&Bh_[bb + (sc + 4) * 8];
        *(uint4*)&Bl[srow][sc * 8]       = *(const uint4*)&Bl_[bb + sc * 8];
        *(uint4*)&Bl[srow][(sc + 4) * 8] = *(const uint4*)&Bl_[bb + (sc + 4) * 8];
        __syncthreads();
        #pragma unroll
        for (int ks = 0; ks < 2; ++ks) {
            bf16x8 a_h = *(const bf16x8*)&Ah[wid * 16 + lc][ks * 32 + kg8];
            bf16x8 a_l = *(const bf16x8*)&Al[wid * 16 + lc][ks * 32 + kg8];
            #pragma unroll
            for (int nt = 0; nt < 4; ++nt) {
                bf16x8 b_h = *(const bf16x8*)&Bh[nt * 16 + lc][ks * 32 + kg8];
                bf16x8 b_l = *(const bf16x8*)&Bl[nt * 16 + lc][ks * 32 + kg8];
                acc[nt] = __builtin_amdgcn_mfma_f32_16x16x32_bf16(a_h, b_h, acc[nt], 0, 0, 0);
                acc[nt] = __builtin_amdgcn_mfma_f32_16x16x32_bf16(a_l, b_h, acc[nt], 0, 0, 0);
                acc[nt] = __builtin_amdgcn_mfma_f32_16x16x32_bf16(a_h, b_l, acc[nt], 0, 0, 0);
            }
        }
    }
    const int orow = i0 + wid * 16 + (lane >> 4) * 4;
    #pragma unroll
    for (int nt = 0; nt < 4; ++nt)
        #pragma unroll
        for (int r = 0; r < 4; ++r)
            C[(size_t)(orow + r) * ldc + j0 + nt * 16 + lc] = acc[nt][r];
}

// ---------------- pairwise dots via MFMA (K=64 head dim), fused split -------------
// C[hh][i][j] = mask * scale_i * dot(A[i,h-slice], B[j,h-slice])
// mode 0: causal (i>=j); mode 1: strict (i>j), row-scaled by beta. Skipped upper
// tiles are never read downstream; masked entries inside written tiles are ZERO.
__global__ __launch_bounds__(256) void pairwise_mfma(const float* __restrict__ A,
    const float* __restrict__ B, const float* __restrict__ beta,
    float* __restrict__ C, int mode, int h0)
{
    const int jt = blockIdx.x, it = blockIdx.y, hh = blockIdx.z;
    if (jt > it) return;
    const int h = h0 + hh;
    __shared__ unsigned short Ah[64][72], Al[64][72], Bh[64][72], Bl[64][72];
    const int tid = threadIdx.x;
    const int i0 = it * 64, j0 = jt * 64;
    const int srow = tid >> 2;
    const int lane = tid & 63, wid = tid >> 6;
    const int lc = lane & 15, kg8 = (lane >> 4) * 8;
    #pragma unroll
    for (int p = 0; p < 4; ++p) {
        const int dd = (tid & 3) * 4 + p * 16;
        float4 a = *(const float4*)&A[(size_t)(i0 + srow) * DMODEL + h * HD + dd];
        split2(a.x, Ah[srow][dd + 0], Al[srow][dd + 0]);
        split2(a.y, Ah[srow][dd + 1], Al[srow][dd + 1]);
        split2(a.z, Ah[srow][dd + 2], Al[srow][dd + 2]);
        split2(a.w, Ah[srow][dd + 3], Al[srow][dd + 3]);
        float4 b = *(const float4*)&B[(size_t)(j0 + srow) * DMODEL + h * HD + dd];
        split2(b.x, Bh[srow][dd + 0], Bl[srow][dd + 0]);
        split2(b.y, Bh[srow][dd + 1], Bl[srow][dd + 1]);
        split2(b.z, Bh[srow][dd + 2], Bl[srow][dd + 2]);
        split2(b.w, Bh[srow][dd + 3], Bl[srow][dd + 3]);
    }
    __syncthreads();
    f32x4 acc[4] = {{0.f,0.f,0.f,0.f},{0.f,0.f,0.f,0.f},{0.f,0.f,0.f,0.f},{0.f,0.f,0.f,0.f}};
    #pragma unroll
    for (int ks = 0; ks < 2; ++ks) {
        bf16x8 a_h = *(const bf16x8*)&Ah[wid * 16 + lc][ks * 32 + kg8];
        bf16x8 a_l = *(const bf16x8*)&Al[wid * 16 + lc][ks * 32 + kg8];
        #pragma unroll
        for (int nt = 0; nt < 4; ++nt) {
            bf16x8 b_h = *(const bf16x8*)&Bh[nt * 16 + lc][ks * 32 + kg8];
            bf16x8 b_l = *(const bf16x8*)&Bl[nt * 16 + lc][ks * 32 + kg8];
            acc[nt] = __builtin_amdgcn_mfma_f32_16x16x32_bf16(a_h, b_h, acc[nt], 0, 0, 0);
            acc[nt] = __builtin_amdgcn_mfma_f32_16x16x32_bf16(a_l, b_h, acc[nt], 0, 0, 0);
            acc[nt] = __builtin_amdgcn_mfma_f32_16x16x32_bf16(a_h, b_l, acc[nt], 0, 0, 0);
        }
    }
    float* Ch = C + (size_t)hh * TSEQ * TSEQ;
    const int orow = i0 + wid * 16 + ((lane >> 4) & 3) * 4;
    #pragma unroll
    for (int r = 0; r < 4; ++r) {
        const int i = orow + r;
        const float sc = (mode == 1) ? beta[i * NH + h] : 1.f;
        #pragma unroll
        for (int nt = 0; nt < 4; ++nt) {
            const int j = j0 + nt * 16 + lc;
            const bool keep = mode ? (i > j) : (i >= j);
            Ch[(size_t)i * TSEQ + j] = keep ? acc[nt][r] * sc : 0.f;
        }
    }
}

// ---------------- S -= G @ Mk via MFMA, fused split, Mk transposed in LDS ---------
__global__ __launch_bounds__(256) void s_update_mfma(float* __restrict__ S,
    const float* __restrict__ G, const float* __restrict__ Mk)
{
    const int jt = blockIdx.x, it = blockIdx.y, hh = blockIdx.z;
    if (jt > it) return;
    const float* Gh = G + (size_t)hh * TSEQ * TSEQ;
    const float* Mh = Mk + (size_t)hh * TSEQ * TSEQ;
    float* Sh = S + (size_t)hh * TSEQ * TSEQ;
    __shared__ unsigned short Ah[64][72], Al[64][72], Bh[64][72], Bl[64][72];
    const int tid = threadIdx.x;
    const int i0 = it * 64, j0 = jt * 64;
    const int srow = tid >> 2;
    const int lane = tid & 63, wid = tid >> 6;
    const int lc = lane & 15, kg8 = (lane >> 4) * 8;
    f32x4 acc[4] = {{0.f,0.f,0.f,0.f},{0.f,0.f,0.f,0.f},{0.f,0.f,0.f,0.f},{0.f,0.f,0.f,0.f}};
    for (int st = jt; st <= it; ++st) {
        const int s0 = st * 64;
        __syncthreads();
        #pragma unroll
        for (int p = 0; p < 4; ++p) {
            const int dd = (tid & 3) * 4 + p * 16;
            // A = G[i][s]: row-major (k = s contiguous)
            float4 g = *(const float4*)&Gh[(size_t)(i0 + srow) * TSEQ + s0 + dd];
            split2(g.x, Ah[srow][dd + 0], Al[srow][dd + 0]);
            split2(g.y, Ah[srow][dd + 1], Al[srow][dd + 1]);
            split2(g.z, Ah[srow][dd + 2], Al[srow][dd + 2]);
            split2(g.w, Ah[srow][dd + 3], Al[srow][dd + 3]);
            // B = Mk[s][j]: stage transposed -> Bh[j][s]
            float4 m = *(const float4*)&Mh[(size_t)(s0 + srow) * TSEQ + j0 + dd];
            split2(m.x, Bh[dd + 0][srow], Bl[dd + 0][srow]);
            split2(m.y, Bh[dd + 1][srow], Bl[dd + 1][srow]);
            split2(m.z, Bh[dd + 2][srow], Bl[dd + 2][srow]);
            split2(m.w, Bh[dd + 3][srow], Bl[dd + 3][srow]);
        }
        __syncthreads();
        #pragma unroll
        for (int ks = 0; ks < 2; ++ks) {
            bf16x8 a_h = *(const bf16x8*)&Ah[wid * 16 + lc][ks * 32 + kg8];
            bf16x8 a_l = *(const bf16x8*)&Al[wid * 16 + lc][ks * 32 + kg8];
            #pragma unroll
            for (int nt = 0; nt < 4; ++nt) {
                bf16x8 b_h = *(const bf16x8*)&Bh[nt * 16 + lc][ks * 32 + kg8];
                bf16x8 b_l = *(const bf16x8*)&Bl[nt * 16 + lc][ks * 32 + kg8];
                acc[nt] = __builtin_amdgcn_mfma_f32_16x16x32_bf16(a_h, b_h, acc[nt], 0, 0, 0);
                acc[nt] = __builtin_amdgcn_mfma_f32_16x16x32_bf16(a_l, b_h, acc[nt], 0, 0, 0);
                acc[nt] = __builtin_amdgcn_mfma_f32_16x16x32_bf16(a_h, b_l, acc[nt], 0, 0, 0);
            }
        }
    }
    const int orow = i0 + wid * 16 + (lane >> 4) * 4;
    #pragma unroll
    for (int nt = 0; nt < 4; ++nt)
        #pragma unroll
        for (int r = 0; r < 4; ++r)
            Sh[(size_t)(orow + r) * TSEQ + j0 + nt * 16 + lc] -= acc[nt][r];
}

// ---------------- generic fp32 tiled GEMM (kept for K=32 wpre) ----------------
__global__ __launch_bounds__(256) void gemm_f32(const float* __restrict__ A,
    const float* __restrict__ B, float* __restrict__ C, int M, int N, int K)
{
    __shared__ float At[16][68];
    __shared__ float Bs[16][68];
    const int tid = threadIdx.x;
    const int tx = tid & 15, ty = tid >> 4;
    const int i0 = blockIdx.y * 64, j0 = blockIdx.x * 64;
    const int arow = tid >> 2, ac4 = (tid & 3) * 4;
    const int brow = tid >> 4, bc4 = (tid & 15) * 4;
    float acc[4][4] = {};
    for (int k0 = 0; k0 < K; k0 += 16) {
        float4 a = *(const float4*)&A[(size_t)(i0 + arow) * K + k0 + ac4];
        At[ac4 + 0][arow] = a.x; At[ac4 + 1][arow] = a.y;
        At[ac4 + 2][arow] = a.z; At[ac4 + 3][arow] = a.w;
        *(float4*)&Bs[brow][bc4] = *(const float4*)&B[(size_t)(k0 + brow) * N + j0 + bc4];
        __syncthreads();
        #pragma unroll
        for (int kk = 0; kk < 16; ++kk) {
            float4 a4 = *(const float4*)&At[kk][ty * 4];
            float4 b4 = *(const float4*)&Bs[kk][tx * 4];
            float av[4] = {a4.x, a4.y, a4.z, a4.w};
            float bv[4] = {b4.x, b4.y, b4.z, b4.w};
            #pragma unroll
            for (int m = 0; m < 4; ++m)
                #pragma unroll
                for (int n = 0; n < 4; ++n)
                    acc[m][n] = fmaf(av[m], bv[n], acc[m][n]);
        }
        __syncthreads();
    }
    #pragma unroll
    for (int m = 0; m < 4; ++m) {
        float4 o = {acc[m][0], acc[m][1], acc[m][2], acc[m][3]};
        *(float4*)&C[(size_t)(i0 + ty * 4 + m) * N + j0 + tx * 4] = o;
    }
}

// ---------------- skinny GEMM (N in {16,32}): row-parallel split-K ----------------
__global__ __launch_bounds__(256) void gemm_skinny_rows(const float* __restrict__ A,
    const float* __restrict__ B, float* __restrict__ C, int N, int K)
{
    const int row = blockIdx.x;
    const int tid = threadIdx.x;
    const int col = tid & (N - 1);
    const int ks = tid / N;
    const int nsl = 256 / N;
    const float* a = A + (size_t)row * K;
    float s = 0.f;
    for (int k = ks; k < K; k += nsl)
        s = fmaf(a[k], B[(size_t)k * N + col], s);
    __shared__ float red[256];
    red[tid] = s; __syncthreads();
    for (int off = 128; off >= N; off >>= 1) {
        if (tid < off) red[tid] += red[tid + off];
        __syncthreads();
    }
    if (tid < N) C[(size_t)row * N + col] = red[tid];
}

// ---------------- causal depthwise conv(3) + SiLU + per-head L2 norm + beta -------
__global__ __launch_bounds__(64) void conv_silu_norm(const float* __restrict__ wpre,
    const float* __restrict__ cw, const float* __restrict__ blog,
    float* __restrict__ w, float* __restrict__ beta)
{
    const int t = blockIdx.x, h = blockIdx.y, d = threadIdx.x;
    const int c = h * HD + d;
    float x2 = wpre[(size_t)t * DMODEL + c];
    float x1 = (t >= 1) ? wpre[(size_t)(t - 1) * DMODEL + c] : 0.f;
    float x0 = (t >= 2) ? wpre[(size_t)(t - 2) * DMODEL + c] : 0.f;
    float y = cw[c * 3 + 0] * x0 + cw[c * 3 + 1] * x1 + cw[c * 3 + 2] * x2;
    y = y / (1.f + expf(-y));
    float ss = y * y;
    #pragma unroll
    for (int off = 32; off >= 1; off >>= 1) ss += __shfl_xor(ss, off, 64);
    float r = 1.f / sqrtf(ss + 1e-6f);
    w[(size_t)t * DMODEL + c] = y * r;
    if (d == 0) beta[t * NH + h] = 2.f / (1.f + expf(-blog[t * NH + h]));
}

// ---------------- blocked triangular solve step for column-chunk c ----------------
__global__ __launch_bounds__(256) void solve_chunk(float* __restrict__ G,
    const float* __restrict__ Mm, int c)
{
    const int rt = c + blockIdx.x;
    const int hh = blockIdx.y;
    float* Gh = G + (size_t)hh * TSEQ * TSEQ;
    const float* Mh = Mm + (size_t)hh * TSEQ * TSEQ;
    __shared__ float T0[64][68];
    __shared__ float T1[64][68];
    const int tid = threadIdx.x, tx = tid & 15, ty = tid >> 4;
    const int i0 = rt * 64, j0 = c * 64;
    const int row = tid >> 2, c4 = (tid & 3) * 4;
    float acc[4][4] = {};
    for (int cp = c + 1; cp <= rt; ++cp) {
        const int s0 = cp * 64;
        #pragma unroll
        for (int p = 0; p < 4; ++p) {
            int dd = c4 + p * 16;
            float4 g = *(const float4*)&Gh[(size_t)(i0 + row) * TSEQ + s0 + dd];
            T0[dd + 0][row] = g.x; T0[dd + 1][row] = g.y;
            T0[dd + 2][row] = g.z; T0[dd + 3][row] = g.w;
            *(float4*)&T1[row][dd] = *(const float4*)&Mh[(size_t)(s0 + row) * TSEQ + j0 + dd];
        }
        __syncthreads();
        #pragma unroll 8
        for (int kk = 0; kk < 64; ++kk) {
            float4 a4 = *(const float4*)&T0[kk][ty * 4];
            float4 b4 = *(const float4*)&T1[kk][tx * 4];
            float av[4] = {a4.x, a4.y, a4.z, a4.w};
            float bv[4] = {b4.x, b4.y, b4.z, b4.w};
            #pragma unroll
            for (int m = 0; m < 4; ++m)
                #pragma unroll
                for (int n = 0; n < 4; ++n)
                    acc[m][n] = fmaf(av[m], bv[n], acc[m][n]);
        }
        __syncthreads();
    }
    #pragma unroll
    for (int m = 0; m < 4; ++m)
        #pragma unroll
        for (int n = 0; n < 4; ++n)
            T0[ty * 4 + m][tx * 4 + n] =
                Gh[(size_t)(i0 + ty * 4 + m) * TSEQ + j0 + tx * 4 + n] - acc[m][n];
    #pragma unroll
    for (int p = 0; p < 4; ++p) {
        int dd = c4 + p * 16;
        *(float4*)&T1[row][dd] = *(const float4*)&Mh[(size_t)(j0 + row) * TSEQ + j0 + dd];
    }
    __syncthreads();
    const int wv = tid >> 6, lane = tid & 63;
    for (int qr = 0; qr < 16; ++qr) {
        const int r_ = wv * 16 + qr;
        float rv = T0[r_][lane];
        for (int s = 63; s >= 1; --s) {
            float g = __shfl(rv, s, 64);
            if (lane < s) rv = fmaf(-g, T1[s][lane], rv);
        }
        Gh[(size_t)(i0 + r_) * TSEQ + j0 + lane] = rv;
    }
}

// ---------------- causal row softmax with D^-0.5 scaling, in place ----------------
__global__ __launch_bounds__(256) void softmax_causal(float* __restrict__ S)
{
    const int i = blockIdx.x, hh = blockIdx.y;
    float* row = S + (size_t)hh * TSEQ * TSEQ + (size_t)i * TSEQ;
    const int tid = threadIdx.x;
    const float sc = 0.125f;
    __shared__ float red[256];
    float mx = -3.4e38f;
    for (int j = tid; j <= i; j += 256) mx = fmaxf(mx, row[j] * sc);
    red[tid] = mx; __syncthreads();
    for (int off = 128; off >= 1; off >>= 1) {
        if (tid < off) red[tid] = fmaxf(red[tid], red[tid + off]);
        __syncthreads();
    }
    mx = red[0]; __syncthreads();
    float sum = 0.f;
    for (int j = tid; j <= i; j += 256) {
        float e = expf(row[j] * sc - mx);
        row[j] = e; sum += e;
    }
    red[tid] = sum; __syncthreads();
    for (int off = 128; off >= 1; off >>= 1) {
        if (tid < off) red[tid] += red[tid + off];
        __syncthreads();
    }
    float inv = 1.f / red[0];
    for (int j = tid; j <= i; j += 256) row[j] *= inv;
}

// ---------------- O[head slice] = P @ V ----------------
__global__ __launch_bounds__(256) void pv64(const float* __restrict__ P,
    const float* __restrict__ V, float* __restrict__ O, int h0)
{
    const int it = blockIdx.x, hh = blockIdx.y, h = h0 + hh;
    const float* Ph = P + (size_t)hh * TSEQ * TSEQ;
    __shared__ float Pt[64][68];
    __shared__ float Vs[64][68];
    const int tid = threadIdx.x, tx = tid & 15, ty = tid >> 4;
    const int i0 = it * 64;
    const int row = tid >> 2, c4 = (tid & 3) * 4;
    float acc[4][4] = {};
    for (int jt = 0; jt <= it; ++jt) {
        const int j0 = jt * 64;
        const int i = i0 + row;
        #pragma unroll
        for (int p = 0; p < 4; ++p) {
            int dd = c4 + p * 16;
            float4 pv = *(const float4*)&Ph[(size_t)i * TSEQ + j0 + dd];
            Pt[dd + 0][row] = (j0 + dd + 0 <= i) ? pv.x : 0.f;
            Pt[dd + 1][row] = (j0 + dd + 1 <= i) ? pv.y : 0.f;
            Pt[dd + 2][row] = (j0 + dd + 2 <= i) ? pv.z : 0.f;
            Pt[dd + 3][row] = (j0 + dd + 3 <= i) ? pv.w : 0.f;
            *(float4*)&Vs[row][dd] = *(const float4*)&V[(size_t)(j0 + row) * DMODEL + h * HD + dd];
        }
        __syncthreads();
        #pragma unroll 8
        for (int kk = 0; kk < 64; ++kk) {
            float4 a4 = *(const float4*)&Pt[kk][ty * 4];
            float4 b4 = *(const float4*)&Vs[kk][tx * 4];
            float av[4] = {a4.x, a4.y, a4.z, a4.w};
            float bv[4] = {b4.x, b4.y, b4.z, b4.w};
            #pragma unroll
            for (int m = 0; m < 4; ++m)
                #pragma unroll
                for (int n = 0; n < 4; ++n)
                    acc[m][n] = fmaf(av[m], bv[n], acc[m][n]);
        }
        __syncthreads();
    }
    #pragma unroll
    for (int m = 0; m < 4; ++m) {
        float4 o = {acc[m][0], acc[m][1], acc[m][2], acc[m][3]};
        *(float4*)&O[(size_t)(i0 + ty * 4 + m) * DMODEL + h * HD + tx * 4] = o;
    }
}

extern "C" void kernel_launch(void* const* d_in, const int* in_sizes, int n_in,
                              void* d_out, int out_size, void* d_ws, size_t ws_size,
                              hipStream_t stream)
{
    const float* x   = (const float*)d_in[0];
    const float* Wq  = (const float*)d_in[1];
    const float* Wk  = (const float*)d_in[2];
    const float* Wv  = (const float*)d_in[3];
    const float* Ww1 = (const float*)d_in[4];
    const float* Ww2 = (const float*)d_in[5];
    const float* cw  = (const float*)d_in[6];
    const float* Wb  = (const float*)d_in[7];
    const float* Wo  = (const float*)d_in[8];
    float* out = (float*)d_out;

    float* ws = (float*)d_ws;
    size_t off = 0;
    auto alloc = [&](size_t n) { float* p = ws + off; off += n; return p; };
    float* q    = alloc((size_t)TSEQ * DMODEL);
    float* k    = alloc((size_t)TSEQ * DMODEL);
    float* v    = alloc((size_t)TSEQ * DMODEL);
    float* w    = alloc((size_t)TSEQ * DMODEL);
    float* wpre = alloc((size_t)TSEQ * DMODEL);
    float* oatt = alloc((size_t)TSEQ * DMODEL);
    float* xw1  = alloc((size_t)TSEQ * RANK);
    float* blog = alloc((size_t)TSEQ * NH);
    float* beta = alloc((size_t)TSEQ * NH);

    // Big region: trio (S, G, M) during the loop; split buffers are OVERLAID on it
    // pre-loop (x + Wq/Wk/Wv splits) and post-loop (oatt + Wo splits) -- time-disjoint.
    int HG = NH;
    while (HG > 1 && (off + 3ull * HG * TSEQ * TSEQ) * sizeof(float) > ws_size) HG >>= 1;
    float* big = ws + off;
    float* Sb = big;
    float* Gb = big + (size_t)HG * TSEQ * TSEQ;
    float* Mb = big + 2ull * HG * TSEQ * TSEQ;

    const size_t E = (size_t)TSEQ * DMODEL;
    unsigned short* us = (unsigned short*)big;
    unsigned short* xs_h  = us;          unsigned short* xs_l  = us + E;
    unsigned short* wqt_h = us + 2 * E;  unsigned short* wqt_l = us + 3 * E;
    unsigned short* wkt_h = us + 4 * E;  unsigned short* wkt_l = us + 5 * E;
    unsigned short* wvt_h = us + 6 * E;  unsigned short* wvt_l = us + 7 * E;
    unsigned short* oat_h = us;          unsigned short* oat_l = us + E;
    unsigned short* wot_h = us + 2 * E;  unsigned short* wot_l = us + 3 * E;

    dim3 g64(DMODEL / 64, TSEQ / 64);
    dim3 gt(16, 16);

    // --- projections via split-bf16 MFMA ---
    split_rm<<<(int)(E / 4 + 255) / 256, 256, 0, stream>>>(x, xs_h, xs_l, (int)(E / 4));
    split_tr<<<gt, 256, 0, stream>>>(Wq, wqt_h, wqt_l, DMODEL, DMODEL);
    split_tr<<<gt, 256, 0, stream>>>(Wk, wkt_h, wkt_l, DMODEL, DMODEL);
    split_tr<<<gt, 256, 0, stream>>>(Wv, wvt_h, wvt_l, DMODEL, DMODEL);
    mfma_nt<<<g64, 256, 0, stream>>>(xs_h, xs_l, DMODEL, wqt_h, wqt_l, DMODEL, q, DMODEL, DMODEL);
    mfma_nt<<<g64, 256, 0, stream>>>(xs_h, xs_l, DMODEL, wkt_h, wkt_l, DMODEL, k, DMODEL, DMODEL);
    mfma_nt<<<g64, 256, 0, stream>>>(xs_h, xs_l, DMODEL, wvt_h, wvt_l, DMODEL, v, DMODEL, DMODEL);
    gemm_skinny_rows<<<TSEQ, 256, 0, stream>>>(x, Ww1, xw1, RANK, DMODEL);
    gemm_f32<<<g64, 256, 0, stream>>>(xw1, Ww2, wpre, TSEQ, DMODEL, RANK);
    gemm_skinny_rows<<<TSEQ, 256, 0, stream>>>(x, Wb, blog, NH, DMODEL);
    conv_silu_norm<<<dim3(TSEQ, NH), 64, 0, stream>>>(wpre, cw, blog, w, beta);

    for (int h0 = 0; h0 < NH; h0 += HG) {
        dim3 gp(16, 16, HG);
        pairwise_mfma<<<gp, 256, 0, stream>>>(w, w, beta, Mb, 1, h0);    // M  (strict, beta)
        pairwise_mfma<<<gp, 256, 0, stream>>>(q, w, nullptr, Gb, 0, h0); // QW (causal) -> RHS
        pairwise_mfma<<<gp, 256, 0, stream>>>(q, k, nullptr, Sb, 0, h0); // QK (causal)
        for (int c = 15; c >= 0; --c)
            solve_chunk<<<dim3(16 - c, HG), 256, 0, stream>>>(Gb, Mb, c);
        pairwise_mfma<<<gp, 256, 0, stream>>>(w, k, beta, Mb, 1, h0);    // Mk (strict, beta)
        s_update_mfma<<<gp, 256, 0, stream>>>(Sb, Gb, Mb);               // S = QK - G Mk
        softmax_causal<<<dim3(TSEQ, HG), 256, 0, stream>>>(Sb);
        pv64<<<dim3(16, HG), 256, 0, stream>>>(Sb, v, oatt, h0);
    }

    // --- final projection via split-bf16 MFMA (overlays trio region, now dead) ---
    split_rm<<<(int)(E / 4 + 255) / 256, 256, 0, stream>>>(oatt, oat_h, oat_l, (int)(E / 4));
    split_tr<<<gt, 256, 0, stream>>>(Wo, wot_h, wot_l, DMODEL, DMODEL);
    mfma_nt<<<g64, 256, 0, stream>>>(oat_h, oat_l, DMODEL, wot_h, wot_l, DMODEL, out, DMODEL, DMODEL);
}

// Round 8
// 914.246 us; speedup vs baseline: 2.3904x; 1.6911x over previous
//
#include <hip/hip_runtime.h>
#include <math.h>

#define TSEQ 1024
#define DMODEL 1024
#define NH 16
#define HD 64
#define RANK 32

typedef __attribute__((ext_vector_type(8))) short bf16x8;
typedef __attribute__((ext_vector_type(4))) float f32x4;

// bf16 split helpers (RNE). hi = bf16(v); lo = bf16(v - hi). ~16 mantissa bits kept.
__device__ __forceinline__ unsigned short f2b(float f) {
    unsigned int u = __float_as_uint(f);
    u += 0x7fffu + ((u >> 16) & 1u);
    return (unsigned short)(u >> 16);
}
__device__ __forceinline__ float b2f(unsigned short h) {
    return __uint_as_float(((unsigned int)h) << 16);
}
__device__ __forceinline__ void split2(float v, unsigned short& h, unsigned short& l) {
    h = f2b(v); l = f2b(v - b2f(h));
}

#define MFMA(a, b, c) __builtin_amdgcn_mfma_f32_16x16x32_bf16((a), (b), (c), 0, 0, 0)

// ---------------- split fp32 -> (hi, lo) bf16, row-major passthrough ----------------
__global__ __launch_bounds__(256) void split_rm(const float* __restrict__ S,
    unsigned short* __restrict__ Hi, unsigned short* __restrict__ Lo, int n4)
{
    int i = blockIdx.x * 256 + threadIdx.x;
    if (i >= n4) return;
    float4 v = *(const float4*)&S[(size_t)i * 4];
    float vv[4] = {v.x, v.y, v.z, v.w};
    unsigned int hw[2], lw[2];
    unsigned short h[4], l[4];
    #pragma unroll
    for (int p = 0; p < 4; ++p) split2(vv[p], h[p], l[p]);
    hw[0] = (unsigned int)h[0] | ((unsigned int)h[1] << 16);
    hw[1] = (unsigned int)h[2] | ((unsigned int)h[3] << 16);
    lw[0] = (unsigned int)l[0] | ((unsigned int)l[1] << 16);
    lw[1] = (unsigned int)l[2] | ((unsigned int)l[3] << 16);
    *(uint2*)&Hi[(size_t)i * 4] = make_uint2(hw[0], hw[1]);
    *(uint2*)&Lo[(size_t)i * 4] = make_uint2(lw[0], lw[1]);
}

// ---------------- split fp32 [K][N] -> transposed (hi, lo) bf16 [N][K] ----------------
__global__ __launch_bounds__(256) void split_tr(const float* __restrict__ S,
    unsigned short* __restrict__ Hi, unsigned short* __restrict__ Lo, int Kd, int Nd)
{
    __shared__ float T[64][65];
    const int i0 = blockIdx.y * 64;
    const int j0 = blockIdx.x * 64;
    const int tid = threadIdx.x;
    const int r = tid >> 2, c16 = (tid & 3) * 16;
    #pragma unroll
    for (int p = 0; p < 4; ++p) {
        float4 v = *(const float4*)&S[(size_t)(i0 + r) * Nd + j0 + c16 + p * 4];
        T[r][c16 + p * 4 + 0] = v.x; T[r][c16 + p * 4 + 1] = v.y;
        T[r][c16 + p * 4 + 2] = v.z; T[r][c16 + p * 4 + 3] = v.w;
    }
    __syncthreads();
    const int orow = tid & 63;
    const int seg = tid >> 6;
    unsigned short hb[16], lb[16];
    #pragma unroll
    for (int p = 0; p < 16; ++p) split2(T[seg * 16 + p][orow], hb[p], lb[p]);
    size_t ob = (size_t)(j0 + orow) * Kd + i0 + seg * 16;
    unsigned int w[4];
    #pragma unroll
    for (int q = 0; q < 2; ++q) {
        #pragma unroll
        for (int p = 0; p < 4; ++p)
            w[p] = (unsigned int)hb[q*8 + 2*p] | ((unsigned int)hb[q*8 + 2*p + 1] << 16);
        *(uint4*)&Hi[ob + q * 8] = make_uint4(w[0], w[1], w[2], w[3]);
        #pragma unroll
        for (int p = 0; p < 4; ++p)
            w[p] = (unsigned int)lb[q*8 + 2*p] | ((unsigned int)lb[q*8 + 2*p + 1] << 16);
        *(uint4*)&Lo[ob + q * 8] = make_uint4(w[0], w[1], w[2], w[3]);
    }
}

// ---------------- split-bf16 MFMA GEMM: C[M,N] = A @ Bt^T (pre-split operands) ------
__global__ __launch_bounds__(256) void mfma_nt(
    const unsigned short* __restrict__ Ah_, const unsigned short* __restrict__ Al_, int lda,
    const unsigned short* __restrict__ Bh_, const unsigned short* __restrict__ Bl_, int ldb,
    float* __restrict__ C, int ldc, int K)
{
    __shared__ unsigned short Ah[64][72], Al[64][72], Bh[64][72], Bl[64][72];
    const int tid = threadIdx.x;
    const int i0 = blockIdx.y * 64, j0 = blockIdx.x * 64;
    const int srow = tid >> 2, sc = tid & 3;
    const int lane = tid & 63, wid = tid >> 6;
    const int lc = lane & 15, kg8 = (lane >> 4) * 8;
    f32x4 acc[4] = {{0.f,0.f,0.f,0.f},{0.f,0.f,0.f,0.f},{0.f,0.f,0.f,0.f},{0.f,0.f,0.f,0.f}};
    for (int k0 = 0; k0 < K; k0 += 64) {
        __syncthreads();
        const size_t ab = (size_t)(i0 + srow) * lda + k0;
        const size_t bb = (size_t)(j0 + srow) * ldb + k0;
        *(uint4*)&Ah[srow][sc * 8]       = *(const uint4*)&Ah_[ab + sc * 8];
        *(uint4*)&Ah[srow][(sc + 4) * 8] = *(const uint4*)&Ah_[ab + (sc + 4) * 8];
        *(uint4*)&Al[srow][sc * 8]       = *(const uint4*)&Al_[ab + sc * 8];
        *(uint4*)&Al[srow][(sc + 4) * 8] = *(const uint4*)&Al_[ab + (sc + 4) * 8];
        *(uint4*)&Bh[srow][sc * 8]       = *(const uint4*)&Bh_[bb + sc * 8];
        *(uint4*)&Bh[srow][(sc + 4) * 8] = *(const uint4*)&Bh_[bb + (sc + 4) * 8];
        *(uint4*)&Bl[srow][sc * 8]       = *(const uint4*)&Bl_[bb + sc * 8];
        *(uint4*)&Bl[srow][(sc + 4) * 8] = *(const uint4*)&Bl_[bb + (sc + 4) * 8];
        __syncthreads();
        #pragma unroll
        for (int ks = 0; ks < 2; ++ks) {
            bf16x8 a_h = *(const bf16x8*)&Ah[wid * 16 + lc][ks * 32 + kg8];
            bf16x8 a_l = *(const bf16x8*)&Al[wid * 16 + lc][ks * 32 + kg8];
            #pragma unroll
            for (int nt = 0; nt < 4; ++nt) {
                bf16x8 b_h = *(const bf16x8*)&Bh[nt * 16 + lc][ks * 32 + kg8];
                bf16x8 b_l = *(const bf16x8*)&Bl[nt * 16 + lc][ks * 32 + kg8];
                acc[nt] = MFMA(a_h, b_h, acc[nt]);
                acc[nt] = MFMA(a_l, b_h, acc[nt]);
                acc[nt] = MFMA(a_h, b_l, acc[nt]);
            }
        }
    }
    const int orow = i0 + wid * 16 + (lane >> 4) * 4;
    #pragma unroll
    for (int nt = 0; nt < 4; ++nt)
        #pragma unroll
        for (int r = 0; r < 4; ++r)
            C[(size_t)(orow + r) * ldc + j0 + nt * 16 + lc] = acc[nt][r];
}

// ---------------- pairwise dots via MFMA, fp32 causal output (QW, QK) -------------
// C[hh][i][j] = (i>=j) ? dot(A[i,h-slice], B[j,h-slice]) : 0
__global__ __launch_bounds__(256) void pairwise_mfma(const float* __restrict__ A,
    const float* __restrict__ B, float* __restrict__ C)
{
    const int jt = blockIdx.x, it = blockIdx.y, hh = blockIdx.z;
    if (jt > it) return;
    __shared__ unsigned short Ah[64][72], Al[64][72], Bh[64][72], Bl[64][72];
    const int tid = threadIdx.x;
    const int i0 = it * 64, j0 = jt * 64;
    const int srow = tid >> 2;
    const int lane = tid & 63, wid = tid >> 6;
    const int lc = lane & 15, kg8 = (lane >> 4) * 8;
    #pragma unroll
    for (int p = 0; p < 4; ++p) {
        const int dd = (tid & 3) * 4 + p * 16;
        float4 a = *(const float4*)&A[(size_t)(i0 + srow) * DMODEL + hh * HD + dd];
        split2(a.x, Ah[srow][dd + 0], Al[srow][dd + 0]);
        split2(a.y, Ah[srow][dd + 1], Al[srow][dd + 1]);
        split2(a.z, Ah[srow][dd + 2], Al[srow][dd + 2]);
        split2(a.w, Ah[srow][dd + 3], Al[srow][dd + 3]);
        float4 b = *(const float4*)&B[(size_t)(j0 + srow) * DMODEL + hh * HD + dd];
        split2(b.x, Bh[srow][dd + 0], Bl[srow][dd + 0]);
        split2(b.y, Bh[srow][dd + 1], Bl[srow][dd + 1]);
        split2(b.z, Bh[srow][dd + 2], Bl[srow][dd + 2]);
        split2(b.w, Bh[srow][dd + 3], Bl[srow][dd + 3]);
    }
    __syncthreads();
    f32x4 acc[4] = {{0.f,0.f,0.f,0.f},{0.f,0.f,0.f,0.f},{0.f,0.f,0.f,0.f},{0.f,0.f,0.f,0.f}};
    #pragma unroll
    for (int ks = 0; ks < 2; ++ks) {
        bf16x8 a_h = *(const bf16x8*)&Ah[wid * 16 + lc][ks * 32 + kg8];
        bf16x8 a_l = *(const bf16x8*)&Al[wid * 16 + lc][ks * 32 + kg8];
        #pragma unroll
        for (int nt = 0; nt < 4; ++nt) {
            bf16x8 b_h = *(const bf16x8*)&Bh[nt * 16 + lc][ks * 32 + kg8];
            bf16x8 b_l = *(const bf16x8*)&Bl[nt * 16 + lc][ks * 32 + kg8];
            acc[nt] = MFMA(a_h, b_h, acc[nt]);
            acc[nt] = MFMA(a_l, b_h, acc[nt]);
            acc[nt] = MFMA(a_h, b_l, acc[nt]);
        }
    }
    float* Ch = C + (size_t)hh * TSEQ * TSEQ;
    const int orow = i0 + wid * 16 + (lane >> 4) * 4;
    #pragma unroll
    for (int r = 0; r < 4; ++r) {
        const int i = orow + r;
        #pragma unroll
        for (int nt = 0; nt < 4; ++nt) {
            const int j = j0 + nt * 16 + lc;
            Ch[(size_t)i * TSEQ + j] = (i >= j) ? acc[nt][r] : 0.f;
        }
    }
}

// ---------------- pairwise -> TRANSPOSED strict-lower bf16 hi/lo output -----------
// Computes V[s][j] = (s>j) ? beta[s]*dot(A[s,h],B[j,h]) : 0 for tile (it=s,jt=j),
// stores TRANSPOSED: Out[hh][j][s] = split(V[s][j]). Tiles jt>it skipped
// (=> Out tiles with col-chunk < row-chunk are never written NOR read).
__global__ __launch_bounds__(256) void pairwise_mt(const float* __restrict__ A,
    const float* __restrict__ B, const float* __restrict__ beta,
    unsigned short* __restrict__ OutH, unsigned short* __restrict__ OutL)
{
    const int jt = blockIdx.x, it = blockIdx.y, hh = blockIdx.z;
    if (jt > it) return;
    __shared__ unsigned short Ah[64][72], Al[64][72], Bh[64][72], Bl[64][72];
    __shared__ float TT[64][68];
    const int tid = threadIdx.x;
    const int i0 = it * 64, j0 = jt * 64;
    const int srow = tid >> 2;
    const int lane = tid & 63, wid = tid >> 6;
    const int lc = lane & 15, kg8 = (lane >> 4) * 8;
    #pragma unroll
    for (int p = 0; p < 4; ++p) {
        const int dd = (tid & 3) * 4 + p * 16;
        float4 a = *(const float4*)&A[(size_t)(i0 + srow) * DMODEL + hh * HD + dd];
        split2(a.x, Ah[srow][dd + 0], Al[srow][dd + 0]);
        split2(a.y, Ah[srow][dd + 1], Al[srow][dd + 1]);
        split2(a.z, Ah[srow][dd + 2], Al[srow][dd + 2]);
        split2(a.w, Ah[srow][dd + 3], Al[srow][dd + 3]);
        float4 b = *(const float4*)&B[(size_t)(j0 + srow) * DMODEL + hh * HD + dd];
        split2(b.x, Bh[srow][dd + 0], Bl[srow][dd + 0]);
        split2(b.y, Bh[srow][dd + 1], Bl[srow][dd + 1]);
        split2(b.z, Bh[srow][dd + 2], Bl[srow][dd + 2]);
        split2(b.w, Bh[srow][dd + 3], Bl[srow][dd + 3]);
    }
    __syncthreads();
    f32x4 acc[4] = {{0.f,0.f,0.f,0.f},{0.f,0.f,0.f,0.f},{0.f,0.f,0.f,0.f},{0.f,0.f,0.f,0.f}};
    #pragma unroll
    for (int ks = 0; ks < 2; ++ks) {
        bf16x8 a_h = *(const bf16x8*)&Ah[wid * 16 + lc][ks * 32 + kg8];
        bf16x8 a_l = *(const bf16x8*)&Al[wid * 16 + lc][ks * 32 + kg8];
        #pragma unroll
        for (int nt = 0; nt < 4; ++nt) {
            bf16x8 b_h = *(const bf16x8*)&Bh[nt * 16 + lc][ks * 32 + kg8];
            bf16x8 b_l = *(const bf16x8*)&Bl[nt * 16 + lc][ks * 32 + kg8];
            acc[nt] = MFMA(a_h, b_h, acc[nt]);
            acc[nt] = MFMA(a_l, b_h, acc[nt]);
            acc[nt] = MFMA(a_h, b_l, acc[nt]);
        }
    }
    // masked+scaled tile -> LDS
    const int rbase = wid * 16 + (lane >> 4) * 4;
    #pragma unroll
    for (int r = 0; r < 4; ++r) {
        const int i = i0 + rbase + r;
        const float sc = beta[i * NH + hh];
        #pragma unroll
        for (int nt = 0; nt < 4; ++nt) {
            const int j = j0 + nt * 16 + lc;
            TT[rbase + r][nt * 16 + lc] = (i > j) ? acc[nt][r] * sc : 0.f;
        }
    }
    __syncthreads();
    // transposed split write: thread -> Out row (j0+srow), cols i0+(tid&3)*16..+16
    const int cb = (tid & 3) * 16;
    unsigned short hb[16], lb[16];
    #pragma unroll
    for (int e = 0; e < 16; ++e) split2(TT[cb + e][srow], hb[e], lb[e]);
    unsigned short* oh = OutH + (size_t)hh * TSEQ * TSEQ + (size_t)(j0 + srow) * TSEQ + i0 + cb;
    unsigned short* ol = OutL + (size_t)hh * TSEQ * TSEQ + (size_t)(j0 + srow) * TSEQ + i0 + cb;
    unsigned int w[4];
    #pragma unroll
    for (int q = 0; q < 2; ++q) {
        #pragma unroll
        for (int p = 0; p < 4; ++p)
            w[p] = (unsigned int)hb[q*8+2*p] | ((unsigned int)hb[q*8+2*p+1] << 16);
        *(uint4*)&oh[q * 8] = make_uint4(w[0], w[1], w[2], w[3]);
        #pragma unroll
        for (int p = 0; p < 4; ++p)
            w[p] = (unsigned int)lb[q*8+2*p] | ((unsigned int)lb[q*8+2*p+1] << 16);
        *(uint4*)&ol[q * 8] = make_uint4(w[0], w[1], w[2], w[3]);
    }
}

// ---------------- invert unit-lower diag blocks: Dt[j][s] = Ainv[s][j] ------------
// A = I + Mcc (strict lower). Mcc[s][t] = Mt[c64+t][c64+s] (hi+lo). One wave/block.
__global__ __launch_bounds__(64) void diag_inv(
    const unsigned short* __restrict__ Mth, const unsigned short* __restrict__ Mtl,
    unsigned short* __restrict__ Dth, unsigned short* __restrict__ Dtl)
{
    const int c = blockIdx.x, hh = blockIdx.y;
    const unsigned short* Mh = Mth + (size_t)hh * TSEQ * TSEQ;
    const unsigned short* Ml = Mtl + (size_t)hh * TSEQ * TSEQ;
    __shared__ float Ms[64][65];   // Ms[s][t] = Mcc[s][t]
    __shared__ float X[64][65];    // X[s][j] = Ainv[s][j]
    const int j = threadIdx.x;     // lane = column (also used as row t for loading)
    const int c64 = c * 64;
    // lane loads Mt row (c64+lane=t), cols s: Ms[s][lane] = Mt[t][s]
    const unsigned short* ph = &Mh[(size_t)(c64 + j) * TSEQ + c64];
    const unsigned short* pl = &Ml[(size_t)(c64 + j) * TSEQ + c64];
    for (int s = 0; s < 64; ++s) Ms[s][j] = b2f(ph[s]) + b2f(pl[s]);
    __builtin_amdgcn_s_waitcnt(0);  // lgkm drain within wave (single-wave block)
    // forward substitution per column j (serial in s, lanes = independent columns)
    for (int s = 0; s < 64; ++s) {
        float val = (s == j) ? 1.f : 0.f;
        for (int t = 0; t < s; ++t)
            val = fmaf(-Ms[s][t], X[t][j], val);
        X[s][j] = val;
    }
    // lane j writes Dt row j: Dt[j][s] = X[s][j]
    unsigned short hb[64], lb[64];
    for (int s = 0; s < 64; ++s) split2(X[s][j], hb[s], lb[s]);
    unsigned short* oh = Dth + (((size_t)hh * 16 + c) * 64 + j) * 64;
    unsigned short* ol = Dtl + (((size_t)hh * 16 + c) * 64 + j) * 64;
    for (int q = 0; q < 8; ++q) {
        unsigned int w[4];
        #pragma unroll
        for (int p = 0; p < 4; ++p)
            w[p] = (unsigned int)hb[q*8+2*p] | ((unsigned int)hb[q*8+2*p+1] << 16);
        *(uint4*)&oh[q * 8] = make_uint4(w[0], w[1], w[2], w[3]);
        #pragma unroll
        for (int p = 0; p < 4; ++p)
            w[p] = (unsigned int)lb[q*8+2*p] | ((unsigned int)lb[q*8+2*p+1] << 16);
        *(uint4*)&ol[q * 8] = make_uint4(w[0], w[1], w[2], w[3]);
    }
}

// ---------------- one-launch triangular solve: G(I+M) = QW -----------------------
// Row-tiles independent: block (rt, head) computes G[rt, c] for c = rt..0.
// acc-MFMA reads G hi/lo tiles this block wrote earlier (barrier-drained).
__global__ __launch_bounds__(256) void solve_row(
    const float* __restrict__ QW,
    const unsigned short* __restrict__ Mth, const unsigned short* __restrict__ Mtl,
    const unsigned short* __restrict__ Dth, const unsigned short* __restrict__ Dtl,
    unsigned short* __restrict__ Gh_, unsigned short* __restrict__ Gl_)
{
    const int rt = blockIdx.x, hh = blockIdx.y;
    const float* QWh = QW + (size_t)hh * TSEQ * TSEQ;
    const unsigned short* Mh = Mth + (size_t)hh * TSEQ * TSEQ;
    const unsigned short* Ml = Mtl + (size_t)hh * TSEQ * TSEQ;
    const unsigned short* Dh = Dth + (size_t)hh * 16 * 4096;
    const unsigned short* Dl = Dtl + (size_t)hh * 16 * 4096;
    unsigned short* Gh = Gh_ + (size_t)hh * TSEQ * TSEQ;
    unsigned short* Gl = Gl_ + (size_t)hh * TSEQ * TSEQ;
    __shared__ float RHS[64][68];
    const int tid = threadIdx.x;
    const int lane = tid & 63, wid = tid >> 6;
    const int lc = lane & 15, kg8 = (lane >> 4) * 8;
    const int rbase = wid * 16 + (lane >> 4) * 4;
    const int i0 = rt * 64;

    for (int c = rt; c >= 0; --c) {
        const int j0 = c * 64;
        f32x4 acc[4] = {{0.f,0.f,0.f,0.f},{0.f,0.f,0.f,0.f},{0.f,0.f,0.f,0.f},{0.f,0.f,0.f,0.f}};
        for (int cp = c + 1; cp <= rt; ++cp) {
            const int s0 = cp * 64;
            #pragma unroll
            for (int ks = 0; ks < 2; ++ks) {
                const size_t ao = (size_t)(i0 + wid * 16 + lc) * TSEQ + s0 + ks * 32 + kg8;
                bf16x8 a_h = *(const bf16x8*)&Gh[ao];
                bf16x8 a_l = *(const bf16x8*)&Gl[ao];
                #pragma unroll
                for (int nt = 0; nt < 4; ++nt) {
                    const size_t bo = (size_t)(j0 + nt * 16 + lc) * TSEQ + s0 + ks * 32 + kg8;
                    bf16x8 b_h = *(const bf16x8*)&Mh[bo];
                    bf16x8 b_l = *(const bf16x8*)&Ml[bo];
                    acc[nt] = MFMA(a_h, b_h, acc[nt]);
                    acc[nt] = MFMA(a_l, b_h, acc[nt]);
                    acc[nt] = MFMA(a_h, b_l, acc[nt]);
                }
            }
        }
        // RHS = QW[rt,c] - acc  -> LDS
        #pragma unroll
        for (int nt = 0; nt < 4; ++nt)
            #pragma unroll
            for (int r = 0; r < 4; ++r)
                RHS[rbase + r][nt * 16 + lc] =
                    QWh[(size_t)(i0 + rbase + r) * TSEQ + j0 + nt * 16 + lc] - acc[nt][r];
        __syncthreads();
        // G[rt,c] = RHS * Dinv(c)   (Dt[j][s] = Dinv[s][j])
        f32x4 g[4] = {{0.f,0.f,0.f,0.f},{0.f,0.f,0.f,0.f},{0.f,0.f,0.f,0.f},{0.f,0.f,0.f,0.f}};
        const unsigned short* Dhc = Dh + c * 4096;
        const unsigned short* Dlc = Dl + c * 4096;
        #pragma unroll
        for (int ks = 0; ks < 2; ++ks) {
            bf16x8 a_h, a_l;
            const float* rp = &RHS[wid * 16 + lc][ks * 32 + kg8];
            #pragma unroll
            for (int e = 0; e < 8; ++e) {
                unsigned short th, tl;
                split2(rp[e], th, tl);
                a_h[e] = (short)th; a_l[e] = (short)tl;
            }
            #pragma unroll
            for (int nt = 0; nt < 4; ++nt) {
                const int bo = (nt * 16 + lc) * 64 + ks * 32 + kg8;
                bf16x8 b_h = *(const bf16x8*)&Dhc[bo];
                bf16x8 b_l = *(const bf16x8*)&Dlc[bo];
                g[nt] = MFMA(a_h, b_h, g[nt]);
                g[nt] = MFMA(a_l, b_h, g[nt]);
                g[nt] = MFMA(a_h, b_l, g[nt]);
            }
        }
        // split & store G tile (read back by later iterations of this block)
        #pragma unroll
        for (int nt = 0; nt < 4; ++nt)
            #pragma unroll
            for (int r = 0; r < 4; ++r) {
                const size_t o = (size_t)(i0 + rbase + r) * TSEQ + j0 + nt * 16 + lc;
                unsigned short th, tl;
                split2(g[nt][r], th, tl);
                Gh[o] = th; Gl[o] = tl;
            }
        __syncthreads();  // drains vmcnt: G stores visible before next iter's loads
    }
}

// ---------------- S -= G @ Mk (pre-split operands, pure-load MFMA) ----------------
__global__ __launch_bounds__(256) void s_update_ps(float* __restrict__ S,
    const unsigned short* __restrict__ Gh_, const unsigned short* __restrict__ Gl_,
    const unsigned short* __restrict__ MktH, const unsigned short* __restrict__ MktL)
{
    const int jt = blockIdx.x, it = blockIdx.y, hh = blockIdx.z;
    if (jt > it) return;
    const unsigned short* Gh = Gh_ + (size_t)hh * TSEQ * TSEQ;
    const unsigned short* Gl = Gl_ + (size_t)hh * TSEQ * TSEQ;
    const unsigned short* Mh = MktH + (size_t)hh * TSEQ * TSEQ;
    const unsigned short* Ml = MktL + (size_t)hh * TSEQ * TSEQ;
    float* Sh = S + (size_t)hh * TSEQ * TSEQ;
    __shared__ unsigned short Ah[64][72], Al[64][72], Bh[64][72], Bl[64][72];
    const int tid = threadIdx.x;
    const int i0 = it * 64, j0 = jt * 64;
    const int srow = tid >> 2, sc = tid & 3;
    const int lane = tid & 63, wid = tid >> 6;
    const int lc = lane & 15, kg8 = (lane >> 4) * 8;
    f32x4 acc[4] = {{0.f,0.f,0.f,0.f},{0.f,0.f,0.f,0.f},{0.f,0.f,0.f,0.f},{0.f,0.f,0.f,0.f}};
    for (int st = jt; st <= it; ++st) {
        const int s0 = st * 64;
        __syncthreads();
        const size_t ab = (size_t)(i0 + srow) * TSEQ + s0;
        const size_t bb = (size_t)(j0 + srow) * TSEQ + s0;
        *(uint4*)&Ah[srow][sc * 8]       = *(const uint4*)&Gh[ab + sc * 8];
        *(uint4*)&Ah[srow][(sc + 4) * 8] = *(const uint4*)&Gh[ab + (sc + 4) * 8];
        *(uint4*)&Al[srow][sc * 8]       = *(const uint4*)&Gl[ab + sc * 8];
        *(uint4*)&Al[srow][(sc + 4) * 8] = *(const uint4*)&Gl[ab + (sc + 4) * 8];
        *(uint4*)&Bh[srow][sc * 8]       = *(const uint4*)&Mh[bb + sc * 8];
        *(uint4*)&Bh[srow][(sc + 4) * 8] = *(const uint4*)&Mh[bb + (sc + 4) * 8];
        *(uint4*)&Bl[srow][sc * 8]       = *(const uint4*)&Ml[bb + sc * 8];
        *(uint4*)&Bl[srow][(sc + 4) * 8] = *(const uint4*)&Ml[bb + (sc + 4) * 8];
        __syncthreads();
        #pragma unroll
        for (int ks = 0; ks < 2; ++ks) {
            bf16x8 a_h = *(const bf16x8*)&Ah[wid * 16 + lc][ks * 32 + kg8];
            bf16x8 a_l = *(const bf16x8*)&Al[wid * 16 + lc][ks * 32 + kg8];
            #pragma unroll
            for (int nt = 0; nt < 4; ++nt) {
                bf16x8 b_h = *(const bf16x8*)&Bh[nt * 16 + lc][ks * 32 + kg8];
                bf16x8 b_l = *(const bf16x8*)&Bl[nt * 16 + lc][ks * 32 + kg8];
                acc[nt] = MFMA(a_h, b_h, acc[nt]);
                acc[nt] = MFMA(a_l, b_h, acc[nt]);
                acc[nt] = MFMA(a_h, b_l, acc[nt]);
            }
        }
    }
    const int orow = i0 + wid * 16 + (lane >> 4) * 4;
    #pragma unroll
    for (int nt = 0; nt < 4; ++nt)
        #pragma unroll
        for (int r = 0; r < 4; ++r)
            Sh[(size_t)(orow + r) * TSEQ + j0 + nt * 16 + lc] -= acc[nt][r];
}

// ---------------- generic fp32 tiled GEMM (kept for K=32 wpre) ----------------
__global__ __launch_bounds__(256) void gemm_f32(const float* __restrict__ A,
    const float* __restrict__ B, float* __restrict__ C, int M, int N, int K)
{
    __shared__ float At[16][68];
    __shared__ float Bs[16][68];
    const int tid = threadIdx.x;
    const int tx = tid & 15, ty = tid >> 4;
    const int i0 = blockIdx.y * 64, j0 = blockIdx.x * 64;
    const int arow = tid >> 2, ac4 = (tid & 3) * 4;
    const int brow = tid >> 4, bc4 = (tid & 15) * 4;
    float acc[4][4] = {};
    for (int k0 = 0; k0 < K; k0 += 16) {
        float4 a = *(const float4*)&A[(size_t)(i0 + arow) * K + k0 + ac4];
        At[ac4 + 0][arow] = a.x; At[ac4 + 1][arow] = a.y;
        At[ac4 + 2][arow] = a.z; At[ac4 + 3][arow] = a.w;
        *(float4*)&Bs[brow][bc4] = *(const float4*)&B[(size_t)(k0 + brow) * N + j0 + bc4];
        __syncthreads();
        #pragma unroll
        for (int kk = 0; kk < 16; ++kk) {
            float4 a4 = *(const float4*)&At[kk][ty * 4];
            float4 b4 = *(const float4*)&Bs[kk][tx * 4];
            float av[4] = {a4.x, a4.y, a4.z, a4.w};
            float bv[4] = {b4.x, b4.y, b4.z, b4.w};
            #pragma unroll
            for (int m = 0; m < 4; ++m)
                #pragma unroll
                for (int n = 0; n < 4; ++n)
                    acc[m][n] = fmaf(av[m], bv[n], acc[m][n]);
        }
        __syncthreads();
    }
    #pragma unroll
    for (int m = 0; m < 4; ++m) {
        float4 o = {acc[m][0], acc[m][1], acc[m][2], acc[m][3]};
        *(float4*)&C[(size_t)(i0 + ty * 4 + m) * N + j0 + tx * 4] = o;
    }
}

// ---------------- skinny GEMM (N in {16,32}): row-parallel split-K ----------------
__global__ __launch_bounds__(256) void gemm_skinny_rows(const float* __restrict__ A,
    const float* __restrict__ B, float* __restrict__ C, int N, int K)
{
    const int row = blockIdx.x;
    const int tid = threadIdx.x;
    const int col = tid & (N - 1);
    const int ks = tid / N;
    const int nsl = 256 / N;
    const float* a = A + (size_t)row * K;
    float s = 0.f;
    for (int k = ks; k < K; k += nsl)
        s = fmaf(a[k], B[(size_t)k * N + col], s);
    __shared__ float red[256];
    red[tid] = s; __syncthreads();
    for (int off = 128; off >= N; off >>= 1) {
        if (tid < off) red[tid] += red[tid + off];
        __syncthreads();
    }
    if (tid < N) C[(size_t)row * N + col] = red[tid];
}

// ---------------- causal depthwise conv(3) + SiLU + per-head L2 norm + beta -------
__global__ __launch_bounds__(64) void conv_silu_norm(const float* __restrict__ wpre,
    const float* __restrict__ cw, const float* __restrict__ blog,
    float* __restrict__ w, float* __restrict__ beta)
{
    const int t = blockIdx.x, h = blockIdx.y, d = threadIdx.x;
    const int c = h * HD + d;
    float x2 = wpre[(size_t)t * DMODEL + c];
    float x1 = (t >= 1) ? wpre[(size_t)(t - 1) * DMODEL + c] : 0.f;
    float x0 = (t >= 2) ? wpre[(size_t)(t - 2) * DMODEL + c] : 0.f;
    float y = cw[c * 3 + 0] * x0 + cw[c * 3 + 1] * x1 + cw[c * 3 + 2] * x2;
    y = y / (1.f + expf(-y));
    float ss = y * y;
    #pragma unroll
    for (int off = 32; off >= 1; off >>= 1) ss += __shfl_xor(ss, off, 64);
    float r = 1.f / sqrtf(ss + 1e-6f);
    w[(size_t)t * DMODEL + c] = y * r;
    if (d == 0) beta[t * NH + h] = 2.f / (1.f + expf(-blog[t * NH + h]));
}

// ---------------- causal row softmax with D^-0.5 scaling, in place ----------------
__global__ __launch_bounds__(256) void softmax_causal(float* __restrict__ S)
{
    const int i = blockIdx.x, hh = blockIdx.y;
    float* row = S + (size_t)hh * TSEQ * TSEQ + (size_t)i * TSEQ;
    const int tid = threadIdx.x;
    const float sc = 0.125f;
    __shared__ float red[256];
    float mx = -3.4e38f;
    for (int j = tid; j <= i; j += 256) mx = fmaxf(mx, row[j] * sc);
    red[tid] = mx; __syncthreads();
    for (int off = 128; off >= 1; off >>= 1) {
        if (tid < off) red[tid] = fmaxf(red[tid], red[tid + off]);
        __syncthreads();
    }
    mx = red[0]; __syncthreads();
    float sum = 0.f;
    for (int j = tid; j <= i; j += 256) {
        float e = expf(row[j] * sc - mx);
        row[j] = e; sum += e;
    }
    red[tid] = sum; __syncthreads();
    for (int off = 128; off >= 1; off >>= 1) {
        if (tid < off) red[tid] += red[tid + off];
        __syncthreads();
    }
    float inv = 1.f / red[0];
    for (int j = tid; j <= i; j += 256) row[j] *= inv;
}

// ---------------- O[head slice] = P @ V ----------------
__global__ __launch_bounds__(256) void pv64(const float* __restrict__ P,
    const float* __restrict__ V, float* __restrict__ O)
{
    const int it = blockIdx.x, hh = blockIdx.y;
    const float* Ph = P + (size_t)hh * TSEQ * TSEQ;
    __shared__ float Pt[64][68];
    __shared__ float Vs[64][68];
    const int tid = threadIdx.x, tx = tid & 15, ty = tid >> 4;
    const int i0 = it * 64;
    const int row = tid >> 2, c4 = (tid & 3) * 4;
    float acc[4][4] = {};
    for (int jt = 0; jt <= it; ++jt) {
        const int j0 = jt * 64;
        const int i = i0 + row;
        #pragma unroll
        for (int p = 0; p < 4; ++p) {
            int dd = c4 + p * 16;
            float4 pv = *(const float4*)&Ph[(size_t)i * TSEQ + j0 + dd];
            Pt[dd + 0][row] = (j0 + dd + 0 <= i) ? pv.x : 0.f;
            Pt[dd + 1][row] = (j0 + dd + 1 <= i) ? pv.y : 0.f;
            Pt[dd + 2][row] = (j0 + dd + 2 <= i) ? pv.z : 0.f;
            Pt[dd + 3][row] = (j0 + dd + 3 <= i) ? pv.w : 0.f;
            *(float4*)&Vs[row][dd] = *(const float4*)&V[(size_t)(j0 + row) * DMODEL + hh * HD + dd];
        }
        __syncthreads();
        #pragma unroll 8
        for (int kk = 0; kk < 64; ++kk) {
            float4 a4 = *(const float4*)&Pt[kk][ty * 4];
            float4 b4 = *(const float4*)&Vs[kk][tx * 4];
            float av[4] = {a4.x, a4.y, a4.z, a4.w};
            float bv[4] = {b4.x, b4.y, b4.z, b4.w};
            #pragma unroll
            for (int m = 0; m < 4; ++m)
                #pragma unroll
                for (int n = 0; n < 4; ++n)
                    acc[m][n] = fmaf(av[m], bv[n], acc[m][n]);
        }
        __syncthreads();
    }
    #pragma unroll
    for (int m = 0; m < 4; ++m) {
        float4 o = {acc[m][0], acc[m][1], acc[m][2], acc[m][3]};
        *(float4*)&O[(size_t)(i0 + ty * 4 + m) * DMODEL + hh * HD + tx * 4] = o;
    }
}

extern "C" void kernel_launch(void* const* d_in, const int* in_sizes, int n_in,
                              void* d_out, int out_size, void* d_ws, size_t ws_size,
                              hipStream_t stream)
{
    const float* x   = (const float*)d_in[0];
    const float* Wq  = (const float*)d_in[1];
    const float* Wk  = (const float*)d_in[2];
    const float* Wv  = (const float*)d_in[3];
    const float* Ww1 = (const float*)d_in[4];
    const float* Ww2 = (const float*)d_in[5];
    const float* cw  = (const float*)d_in[6];
    const float* Wb  = (const float*)d_in[7];
    const float* Wo  = (const float*)d_in[8];
    float* out = (float*)d_out;

    float* ws = (float*)d_ws;
    size_t off = 0;
    auto alloc = [&](size_t n) { float* p = ws + off; off += n; return p; };
    float* q    = alloc((size_t)TSEQ * DMODEL);
    float* k    = alloc((size_t)TSEQ * DMODEL);
    float* v    = alloc((size_t)TSEQ * DMODEL);
    float* w    = alloc((size_t)TSEQ * DMODEL);
    float* wpre = alloc((size_t)TSEQ * DMODEL);   // reused as Dinv hi/lo after conv
    float* oatt = alloc((size_t)TSEQ * DMODEL);
    float* xw1  = alloc((size_t)TSEQ * RANK);
    float* blog = alloc((size_t)TSEQ * NH);
    float* beta = alloc((size_t)TSEQ * NH);

    // Three 64MB slots (same 216MB footprint as validated HG=16 rounds):
    //  slot0: QW fp32 -> (after solve) S fp32
    //  slot1: Mt hi/lo -> (after solve) Mkt hi/lo
    //  slot2: G hi/lo
    const size_t HT = (size_t)NH * TSEQ * TSEQ;   // 16M elems
    float* slot0 = ws + off;
    float* slot1 = slot0 + HT;
    float* slot2 = slot1 + HT;
    unsigned short* MtH = (unsigned short*)slot1;
    unsigned short* MtL = MtH + HT;
    unsigned short* GH  = (unsigned short*)slot2;
    unsigned short* GL  = GH + HT;
    unsigned short* DtH = (unsigned short*)wpre;            // 16*16*4096 = 1M shorts
    unsigned short* DtL = DtH + (size_t)NH * 16 * 4096;     // second 1M shorts (4MB tot)

    const size_t E = (size_t)TSEQ * DMODEL;
    unsigned short* us = (unsigned short*)slot0;  // projection split overlays (pre/post)
    unsigned short* xs_h  = us;          unsigned short* xs_l  = us + E;
    unsigned short* wqt_h = us + 2 * E;  unsigned short* wqt_l = us + 3 * E;
    unsigned short* wkt_h = us + 4 * E;  unsigned short* wkt_l = us + 5 * E;
    unsigned short* wvt_h = us + 6 * E;  unsigned short* wvt_l = us + 7 * E;
    unsigned short* oat_h = us;          unsigned short* oat_l = us + E;
    unsigned short* wot_h = us + 2 * E;  unsigned short* wot_l = us + 3 * E;

    dim3 g64(DMODEL / 64, TSEQ / 64);
    dim3 gt(16, 16);
    dim3 gp(16, 16, NH);

    // --- projections via split-bf16 MFMA ---
    split_rm<<<(int)(E / 4 + 255) / 256, 256, 0, stream>>>(x, xs_h, xs_l, (int)(E / 4));
    split_tr<<<gt, 256, 0, stream>>>(Wq, wqt_h, wqt_l, DMODEL, DMODEL);
    split_tr<<<gt, 256, 0, stream>>>(Wk, wkt_h, wkt_l, DMODEL, DMODEL);
    split_tr<<<gt, 256, 0, stream>>>(Wv, wvt_h, wvt_l, DMODEL, DMODEL);
    mfma_nt<<<g64, 256, 0, stream>>>(xs_h, xs_l, DMODEL, wqt_h, wqt_l, DMODEL, q, DMODEL, DMODEL);
    mfma_nt<<<g64, 256, 0, stream>>>(xs_h, xs_l, DMODEL, wkt_h, wkt_l, DMODEL, k, DMODEL, DMODEL);
    mfma_nt<<<g64, 256, 0, stream>>>(xs_h, xs_l, DMODEL, wvt_h, wvt_l, DMODEL, v, DMODEL, DMODEL);
    gemm_skinny_rows<<<TSEQ, 256, 0, stream>>>(x, Ww1, xw1, RANK, DMODEL);
    gemm_f32<<<g64, 256, 0, stream>>>(xw1, Ww2, wpre, TSEQ, DMODEL, RANK);
    gemm_skinny_rows<<<TSEQ, 256, 0, stream>>>(x, Wb, blog, NH, DMODEL);
    conv_silu_norm<<<dim3(TSEQ, NH), 64, 0, stream>>>(wpre, cw, blog, w, beta);

    // --- UT-transform path ---
    pairwise_mt<<<gp, 256, 0, stream>>>(w, w, beta, MtH, MtL);        // Mt = (beta w w^T)^T, split
    diag_inv<<<dim3(16, NH), 64, 0, stream>>>(MtH, MtL, DtH, DtL);    // Dinv^T per diag block
    pairwise_mfma<<<gp, 256, 0, stream>>>(q, w, slot0);               // QW (causal, fp32)
    solve_row<<<dim3(16, NH), 256, 0, stream>>>(slot0, MtH, MtL, DtH, DtL, GH, GL);
    pairwise_mt<<<gp, 256, 0, stream>>>(w, k, beta, MtH, MtL);        // Mkt (reuses slot1)
    pairwise_mfma<<<gp, 256, 0, stream>>>(q, k, slot0);               // S = QK (reuses slot0)
    s_update_ps<<<gp, 256, 0, stream>>>(slot0, GH, GL, MtH, MtL);     // S -= G Mk
    softmax_causal<<<dim3(TSEQ, NH), 256, 0, stream>>>(slot0);
    pv64<<<dim3(16, NH), 256, 0, stream>>>(slot0, v, oatt);

    // --- final projection via split-bf16 MFMA (slot0 dead -> overlay splits) ---
    split_rm<<<(int)(E / 4 + 255) / 256, 256, 0, stream>>>(oatt, oat_h, oat_l, (int)(E / 4));
    split_tr<<<gt, 256, 0, stream>>>(Wo, wot_h, wot_l, DMODEL, DMODEL);
    mfma_nt<<<g64, 256, 0, stream>>>(oat_h, oat_l, DMODEL, wot_h, wot_l, DMODEL, out, DMODEL, DMODEL);
}

// Round 10
// 768.532 us; speedup vs baseline: 2.8436x; 1.1896x over previous
//
#include <hip/hip_runtime.h>
#include <math.h>

#define TSEQ 1024
#define DMODEL 1024
#define NH 16
#define HD 64
#define RANK 32

typedef __attribute__((ext_vector_type(8))) short bf16x8;
typedef __attribute__((ext_vector_type(4))) float f32x4;

// bf16 split helpers (RNE). hi = bf16(v); lo = bf16(v - hi). ~16 mantissa bits kept.
__device__ __forceinline__ unsigned short f2b(float f) {
    unsigned int u = __float_as_uint(f);
    u += 0x7fffu + ((u >> 16) & 1u);
    return (unsigned short)(u >> 16);
}
__device__ __forceinline__ float b2f(unsigned short h) {
    return __uint_as_float(((unsigned int)h) << 16);
}
__device__ __forceinline__ void split2(float v, unsigned short& h, unsigned short& l) {
    h = f2b(v); l = f2b(v - b2f(h));
}

#define MFMA(a, b, c) __builtin_amdgcn_mfma_f32_16x16x32_bf16((a), (b), (c), 0, 0, 0)

// ---------------- split fp32 -> (hi, lo) bf16, row-major passthrough ----------------
__global__ __launch_bounds__(256) void split_rm(const float* __restrict__ S,
    unsigned short* __restrict__ Hi, unsigned short* __restrict__ Lo, int n4)
{
    int i = blockIdx.x * 256 + threadIdx.x;
    if (i >= n4) return;
    float4 v = *(const float4*)&S[(size_t)i * 4];
    float vv[4] = {v.x, v.y, v.z, v.w};
    unsigned int hw[2], lw[2];
    unsigned short h[4], l[4];
    #pragma unroll
    for (int p = 0; p < 4; ++p) split2(vv[p], h[p], l[p]);
    hw[0] = (unsigned int)h[0] | ((unsigned int)h[1] << 16);
    hw[1] = (unsigned int)h[2] | ((unsigned int)h[3] << 16);
    lw[0] = (unsigned int)l[0] | ((unsigned int)l[1] << 16);
    lw[1] = (unsigned int)l[2] | ((unsigned int)l[3] << 16);
    *(uint2*)&Hi[(size_t)i * 4] = make_uint2(hw[0], hw[1]);
    *(uint2*)&Lo[(size_t)i * 4] = make_uint2(lw[0], lw[1]);
}

// ---------------- split fp32 [K][N] -> transposed (hi, lo) bf16 [N][K] ----------------
__global__ __launch_bounds__(256) void split_tr(const float* __restrict__ S,
    unsigned short* __restrict__ Hi, unsigned short* __restrict__ Lo, int Kd, int Nd)
{
    __shared__ float T[64][65];
    const int i0 = blockIdx.y * 64;
    const int j0 = blockIdx.x * 64;
    const int tid = threadIdx.x;
    const int r = tid >> 2, c16 = (tid & 3) * 16;
    #pragma unroll
    for (int p = 0; p < 4; ++p) {
        float4 v = *(const float4*)&S[(size_t)(i0 + r) * Nd + j0 + c16 + p * 4];
        T[r][c16 + p * 4 + 0] = v.x; T[r][c16 + p * 4 + 1] = v.y;
        T[r][c16 + p * 4 + 2] = v.z; T[r][c16 + p * 4 + 3] = v.w;
    }
    __syncthreads();
    const int orow = tid & 63;
    const int seg = tid >> 6;
    unsigned short hb[16], lb[16];
    #pragma unroll
    for (int p = 0; p < 16; ++p) split2(T[seg * 16 + p][orow], hb[p], lb[p]);
    size_t ob = (size_t)(j0 + orow) * Kd + i0 + seg * 16;
    unsigned int w[4];
    #pragma unroll
    for (int q = 0; q < 2; ++q) {
        #pragma unroll
        for (int p = 0; p < 4; ++p)
            w[p] = (unsigned int)hb[q*8 + 2*p] | ((unsigned int)hb[q*8 + 2*p + 1] << 16);
        *(uint4*)&Hi[ob + q * 8] = make_uint4(w[0], w[1], w[2], w[3]);
        #pragma unroll
        for (int p = 0; p < 4; ++p)
            w[p] = (unsigned int)lb[q*8 + 2*p] | ((unsigned int)lb[q*8 + 2*p + 1] << 16);
        *(uint4*)&Lo[ob + q * 8] = make_uint4(w[0], w[1], w[2], w[3]);
    }
}

// ---------------- split-bf16 MFMA GEMM: C[M,N] = A @ Bt^T (pre-split operands) ------
__global__ __launch_bounds__(256) void mfma_nt(
    const unsigned short* __restrict__ Ah_, const unsigned short* __restrict__ Al_, int lda,
    const unsigned short* __restrict__ Bh_, const unsigned short* __restrict__ Bl_, int ldb,
    float* __restrict__ C, int ldc, int K)
{
    __shared__ unsigned short Ah[64][72], Al[64][72], Bh[64][72], Bl[64][72];
    const int tid = threadIdx.x;
    const int i0 = blockIdx.y * 64, j0 = blockIdx.x * 64;
    const int srow = tid >> 2, sc = tid & 3;
    const int lane = tid & 63, wid = tid >> 6;
    const int lc = lane & 15, kg8 = (lane >> 4) * 8;
    f32x4 acc[4] = {{0.f,0.f,0.f,0.f},{0.f,0.f,0.f,0.f},{0.f,0.f,0.f,0.f},{0.f,0.f,0.f,0.f}};
    for (int k0 = 0; k0 < K; k0 += 64) {
        __syncthreads();
        const size_t ab = (size_t)(i0 + srow) * lda + k0;
        const size_t bb = (size_t)(j0 + srow) * ldb + k0;
        *(uint4*)&Ah[srow][sc * 8]       = *(const uint4*)&Ah_[ab + sc * 8];
        *(uint4*)&Ah[srow][(sc + 4) * 8] = *(const uint4*)&Ah_[ab + (sc + 4) * 8];
        *(uint4*)&Al[srow][sc * 8]       = *(const uint4*)&Al_[ab + sc * 8];
        *(uint4*)&Al[srow][(sc + 4) * 8] = *(const uint4*)&Al_[ab + (sc + 4) * 8];
        *(uint4*)&Bh[srow][sc * 8]       = *(const uint4*)&Bh_[bb + sc * 8];
        *(uint4*)&Bh[srow][(sc + 4) * 8] = *(const uint4*)&Bh_[bb + (sc + 4) * 8];
        *(uint4*)&Bl[srow][sc * 8]       = *(const uint4*)&Bl_[bb + sc * 8];
        *(uint4*)&Bl[srow][(sc + 4) * 8] = *(const uint4*)&Bl_[bb + (sc + 4) * 8];
        __syncthreads();
        #pragma unroll
        for (int ks = 0; ks < 2; ++ks) {
            bf16x8 a_h = *(const bf16x8*)&Ah[wid * 16 + lc][ks * 32 + kg8];
            bf16x8 a_l = *(const bf16x8*)&Al[wid * 16 + lc][ks * 32 + kg8];
            #pragma unroll
            for (int nt = 0; nt < 4; ++nt) {
                bf16x8 b_h = *(const bf16x8*)&Bh[nt * 16 + lc][ks * 32 + kg8];
                bf16x8 b_l = *(const bf16x8*)&Bl[nt * 16 + lc][ks * 32 + kg8];
                acc[nt] = MFMA(a_h, b_h, acc[nt]);
                acc[nt] = MFMA(a_l, b_h, acc[nt]);
                acc[nt] = MFMA(a_h, b_l, acc[nt]);
            }
        }
    }
    const int orow = i0 + wid * 16 + (lane >> 4) * 4;
    #pragma unroll
    for (int nt = 0; nt < 4; ++nt)
        #pragma unroll
        for (int r = 0; r < 4; ++r)
            C[(size_t)(orow + r) * ldc + j0 + nt * 16 + lc] = acc[nt][r];
}

// ---------------- pairwise dots via MFMA, fp32 causal output (QW, QK) -------------
__global__ __launch_bounds__(256) void pairwise_mfma(const float* __restrict__ A,
    const float* __restrict__ B, float* __restrict__ C)
{
    const int jt = blockIdx.x, it = blockIdx.y, hh = blockIdx.z;
    if (jt > it) return;
    __shared__ unsigned short Ah[64][72], Al[64][72], Bh[64][72], Bl[64][72];
    const int tid = threadIdx.x;
    const int i0 = it * 64, j0 = jt * 64;
    const int srow = tid >> 2;
    const int lane = tid & 63, wid = tid >> 6;
    const int lc = lane & 15, kg8 = (lane >> 4) * 8;
    #pragma unroll
    for (int p = 0; p < 4; ++p) {
        const int dd = (tid & 3) * 4 + p * 16;
        float4 a = *(const float4*)&A[(size_t)(i0 + srow) * DMODEL + hh * HD + dd];
        split2(a.x, Ah[srow][dd + 0], Al[srow][dd + 0]);
        split2(a.y, Ah[srow][dd + 1], Al[srow][dd + 1]);
        split2(a.z, Ah[srow][dd + 2], Al[srow][dd + 2]);
        split2(a.w, Ah[srow][dd + 3], Al[srow][dd + 3]);
        float4 b = *(const float4*)&B[(size_t)(j0 + srow) * DMODEL + hh * HD + dd];
        split2(b.x, Bh[srow][dd + 0], Bl[srow][dd + 0]);
        split2(b.y, Bh[srow][dd + 1], Bl[srow][dd + 1]);
        split2(b.z, Bh[srow][dd + 2], Bl[srow][dd + 2]);
        split2(b.w, Bh[srow][dd + 3], Bl[srow][dd + 3]);
    }
    __syncthreads();
    f32x4 acc[4] = {{0.f,0.f,0.f,0.f},{0.f,0.f,0.f,0.f},{0.f,0.f,0.f,0.f},{0.f,0.f,0.f,0.f}};
    #pragma unroll
    for (int ks = 0; ks < 2; ++ks) {
        bf16x8 a_h = *(const bf16x8*)&Ah[wid * 16 + lc][ks * 32 + kg8];
        bf16x8 a_l = *(const bf16x8*)&Al[wid * 16 + lc][ks * 32 + kg8];
        #pragma unroll
        for (int nt = 0; nt < 4; ++nt) {
            bf16x8 b_h = *(const bf16x8*)&Bh[nt * 16 + lc][ks * 32 + kg8];
            bf16x8 b_l = *(const bf16x8*)&Bl[nt * 16 + lc][ks * 32 + kg8];
            acc[nt] = MFMA(a_h, b_h, acc[nt]);
            acc[nt] = MFMA(a_l, b_h, acc[nt]);
            acc[nt] = MFMA(a_h, b_l, acc[nt]);
        }
    }
    float* Ch = C + (size_t)hh * TSEQ * TSEQ;
    const int orow = i0 + wid * 16 + (lane >> 4) * 4;
    #pragma unroll
    for (int r = 0; r < 4; ++r) {
        const int i = orow + r;
        #pragma unroll
        for (int nt = 0; nt < 4; ++nt) {
            const int j = j0 + nt * 16 + lc;
            Ch[(size_t)i * TSEQ + j] = (i >= j) ? acc[nt][r] : 0.f;
        }
    }
}

// ---------------- pairwise -> TRANSPOSED strict-lower bf16 hi/lo output -----------
__global__ __launch_bounds__(256) void pairwise_mt(const float* __restrict__ A,
    const float* __restrict__ B, const float* __restrict__ beta,
    unsigned short* __restrict__ OutH, unsigned short* __restrict__ OutL)
{
    const int jt = blockIdx.x, it = blockIdx.y, hh = blockIdx.z;
    if (jt > it) return;
    __shared__ unsigned short Ah[64][72], Al[64][72], Bh[64][72], Bl[64][72];
    __shared__ float TT[64][68];
    const int tid = threadIdx.x;
    const int i0 = it * 64, j0 = jt * 64;
    const int srow = tid >> 2;
    const int lane = tid & 63, wid = tid >> 6;
    const int lc = lane & 15, kg8 = (lane >> 4) * 8;
    #pragma unroll
    for (int p = 0; p < 4; ++p) {
        const int dd = (tid & 3) * 4 + p * 16;
        float4 a = *(const float4*)&A[(size_t)(i0 + srow) * DMODEL + hh * HD + dd];
        split2(a.x, Ah[srow][dd + 0], Al[srow][dd + 0]);
        split2(a.y, Ah[srow][dd + 1], Al[srow][dd + 1]);
        split2(a.z, Ah[srow][dd + 2], Al[srow][dd + 2]);
        split2(a.w, Ah[srow][dd + 3], Al[srow][dd + 3]);
        float4 b = *(const float4*)&B[(size_t)(j0 + srow) * DMODEL + hh * HD + dd];
        split2(b.x, Bh[srow][dd + 0], Bl[srow][dd + 0]);
        split2(b.y, Bh[srow][dd + 1], Bl[srow][dd + 1]);
        split2(b.z, Bh[srow][dd + 2], Bl[srow][dd + 2]);
        split2(b.w, Bh[srow][dd + 3], Bl[srow][dd + 3]);
    }
    __syncthreads();
    f32x4 acc[4] = {{0.f,0.f,0.f,0.f},{0.f,0.f,0.f,0.f},{0.f,0.f,0.f,0.f},{0.f,0.f,0.f,0.f}};
    #pragma unroll
    for (int ks = 0; ks < 2; ++ks) {
        bf16x8 a_h = *(const bf16x8*)&Ah[wid * 16 + lc][ks * 32 + kg8];
        bf16x8 a_l = *(const bf16x8*)&Al[wid * 16 + lc][ks * 32 + kg8];
        #pragma unroll
        for (int nt = 0; nt < 4; ++nt) {
            bf16x8 b_h = *(const bf16x8*)&Bh[nt * 16 + lc][ks * 32 + kg8];
            bf16x8 b_l = *(const bf16x8*)&Bl[nt * 16 + lc][ks * 32 + kg8];
            acc[nt] = MFMA(a_h, b_h, acc[nt]);
            acc[nt] = MFMA(a_l, b_h, acc[nt]);
            acc[nt] = MFMA(a_h, b_l, acc[nt]);
        }
    }
    const int rbase = wid * 16 + (lane >> 4) * 4;
    #pragma unroll
    for (int r = 0; r < 4; ++r) {
        const int i = i0 + rbase + r;
        const float sc = beta[i * NH + hh];
        #pragma unroll
        for (int nt = 0; nt < 4; ++nt) {
            const int j = j0 + nt * 16 + lc;
            TT[rbase + r][nt * 16 + lc] = (i > j) ? acc[nt][r] * sc : 0.f;
        }
    }
    __syncthreads();
    const int cb = (tid & 3) * 16;
    unsigned short hb[16], lb[16];
    #pragma unroll
    for (int e = 0; e < 16; ++e) split2(TT[cb + e][srow], hb[e], lb[e]);
    unsigned short* oh = OutH + (size_t)hh * TSEQ * TSEQ + (size_t)(j0 + srow) * TSEQ + i0 + cb;
    unsigned short* ol = OutL + (size_t)hh * TSEQ * TSEQ + (size_t)(j0 + srow) * TSEQ + i0 + cb;
    unsigned int w[4];
    #pragma unroll
    for (int q = 0; q < 2; ++q) {
        #pragma unroll
        for (int p = 0; p < 4; ++p)
            w[p] = (unsigned int)hb[q*8+2*p] | ((unsigned int)hb[q*8+2*p+1] << 16);
        *(uint4*)&oh[q * 8] = make_uint4(w[0], w[1], w[2], w[3]);
        #pragma unroll
        for (int p = 0; p < 4; ++p)
            w[p] = (unsigned int)lb[q*8+2*p] | ((unsigned int)lb[q*8+2*p+1] << 16);
        *(uint4*)&ol[q * 8] = make_uint4(w[0], w[1], w[2], w[3]);
    }
}

// ---------------- invert unit-lower diag blocks: Dt[j][s] = Ainv[s][j] ------------
__global__ __launch_bounds__(64) void diag_inv(
    const unsigned short* __restrict__ Mth, const unsigned short* __restrict__ Mtl,
    unsigned short* __restrict__ Dth, unsigned short* __restrict__ Dtl)
{
    const int c = blockIdx.x, hh = blockIdx.y;
    const unsigned short* Mh = Mth + (size_t)hh * TSEQ * TSEQ;
    const unsigned short* Ml = Mtl + (size_t)hh * TSEQ * TSEQ;
    __shared__ float Ms[64][65];
    __shared__ float X[64][65];
    const int j = threadIdx.x;
    const int c64 = c * 64;
    const unsigned short* ph = &Mh[(size_t)(c64 + j) * TSEQ + c64];
    const unsigned short* pl = &Ml[(size_t)(c64 + j) * TSEQ + c64];
    for (int s = 0; s < 64; ++s) Ms[s][j] = b2f(ph[s]) + b2f(pl[s]);
    __builtin_amdgcn_s_waitcnt(0);
    for (int s = 0; s < 64; ++s) {
        float val = (s == j) ? 1.f : 0.f;
        for (int t = 0; t < s; ++t)
            val = fmaf(-Ms[s][t], X[t][j], val);
        X[s][j] = val;
    }
    unsigned short hb[64], lb[64];
    for (int s = 0; s < 64; ++s) split2(X[s][j], hb[s], lb[s]);
    unsigned short* oh = Dth + (((size_t)hh * 16 + c) * 64 + j) * 64;
    unsigned short* ol = Dtl + (((size_t)hh * 16 + c) * 64 + j) * 64;
    for (int q = 0; q < 8; ++q) {
        unsigned int w[4];
        #pragma unroll
        for (int p = 0; p < 4; ++p)
            w[p] = (unsigned int)hb[q*8+2*p] | ((unsigned int)hb[q*8+2*p+1] << 16);
        *(uint4*)&oh[q * 8] = make_uint4(w[0], w[1], w[2], w[3]);
        #pragma unroll
        for (int p = 0; p < 4; ++p)
            w[p] = (unsigned int)lb[q*8+2*p] | ((unsigned int)lb[q*8+2*p+1] << 16);
        *(uint4*)&ol[q * 8] = make_uint4(w[0], w[1], w[2], w[3]);
    }
}

// ---------------- one-launch triangular solve, 16-row strips ----------------------
// G(I+M) = QW. Rows independent -> strip of 16 rows per block, grid (64, NH).
// Per c (descending): acc = sum_{cp>c} G[strip,cp] @ M[cp,c] via LDS-staged MFMA;
// RHS = QW - acc; G[strip,c] = RHS * Dinv(c); split-store (read back at later c).
__global__ __launch_bounds__(256) void solve_row16(
    const float* __restrict__ QW,
    const unsigned short* __restrict__ Mth, const unsigned short* __restrict__ Mtl,
    const unsigned short* __restrict__ Dth, const unsigned short* __restrict__ Dtl,
    unsigned short* __restrict__ Gh_, unsigned short* __restrict__ Gl_)
{
    const int hh = blockIdx.y;
    const int i0 = blockIdx.x * 16;          // strip base row
    const int cmax = blockIdx.x >> 2;        // 64-chunk containing the strip
    const float* QWh = QW + (size_t)hh * TSEQ * TSEQ;
    const unsigned short* Mh = Mth + (size_t)hh * TSEQ * TSEQ;
    const unsigned short* Ml = Mtl + (size_t)hh * TSEQ * TSEQ;
    const unsigned short* Dh = Dth + (size_t)hh * 16 * 4096;
    const unsigned short* Dl = Dtl + (size_t)hh * 16 * 4096;
    unsigned short* Gh = Gh_ + (size_t)hh * TSEQ * TSEQ;
    unsigned short* Gl = Gl_ + (size_t)hh * TSEQ * TSEQ;

    __shared__ unsigned short As_h[16][72], As_l[16][72];   // G strip tile (16 x 64)
    __shared__ unsigned short Bs_h[64][72], Bs_l[64][72];   // Mt tile (64 x 64)
    __shared__ float RHS[16][68];

    const int tid = threadIdx.x;
    const int lane = tid & 63, wid = tid >> 6;   // wave -> 16-col group
    const int lc = lane & 15, kg8 = (lane >> 4) * 8;
    const int rb = (lane >> 4) * 4;              // output row base within strip

    for (int c = cmax; c >= 0; --c) {
        const int j0 = c * 64;
        f32x4 acc = {0.f, 0.f, 0.f, 0.f};
        for (int cp = c + 1; cp <= cmax; ++cp) {
            const int s0 = cp * 64;
            // stage A = G[strip, cp] (threads 0..127 -> hi, 128..255 -> lo)
            {
                const int t7 = tid & 127;
                const int ar = t7 >> 3, ac8 = (t7 & 7) * 8;
                const size_t go = (size_t)(i0 + ar) * TSEQ + s0 + ac8;
                if (tid < 128) *(uint4*)&As_h[ar][ac8] = *(const uint4*)&Gh[go];
                else           *(uint4*)&As_l[ar][ac8] = *(const uint4*)&Gl[go];
            }
            // stage B = Mt[j0..+64, s0..+64] hi/lo
            {
                const int br = tid >> 2, bc = (tid & 3) * 16;
                const size_t go = (size_t)(j0 + br) * TSEQ + s0 + bc;
                *(uint4*)&Bs_h[br][bc]     = *(const uint4*)&Mh[go];
                *(uint4*)&Bs_h[br][bc + 8] = *(const uint4*)&Mh[go + 8];
                *(uint4*)&Bs_l[br][bc]     = *(const uint4*)&Ml[go];
                *(uint4*)&Bs_l[br][bc + 8] = *(const uint4*)&Ml[go + 8];
            }
            __syncthreads();
            #pragma unroll
            for (int ks = 0; ks < 2; ++ks) {
                bf16x8 a_h = *(const bf16x8*)&As_h[lc][ks * 32 + kg8];
                bf16x8 a_l = *(const bf16x8*)&As_l[lc][ks * 32 + kg8];
                bf16x8 b_h = *(const bf16x8*)&Bs_h[wid * 16 + lc][ks * 32 + kg8];
                bf16x8 b_l = *(const bf16x8*)&Bs_l[wid * 16 + lc][ks * 32 + kg8];
                acc = MFMA(a_h, b_h, acc);
                acc = MFMA(a_l, b_h, acc);
                acc = MFMA(a_h, b_l, acc);
            }
            __syncthreads();
        }
        // RHS = QW[strip, c] - acc  (wave w owns cols w*16..+16)
        #pragma unroll
        for (int r = 0; r < 4; ++r)
            RHS[rb + r][wid * 16 + lc] =
                QWh[(size_t)(i0 + rb + r) * TSEQ + j0 + wid * 16 + lc] - acc[r];
        __syncthreads();
        // G[strip, c] = RHS * Dinv(c);  Dt[j][s] = Dinv[s][j]
        f32x4 g = {0.f, 0.f, 0.f, 0.f};
        const unsigned short* Dhc = Dh + c * 4096;
        const unsigned short* Dlc = Dl + c * 4096;
        #pragma unroll
        for (int ks = 0; ks < 2; ++ks) {
            bf16x8 a_h, a_l;
            const float* rp = &RHS[lc][ks * 32 + kg8];
            #pragma unroll
            for (int e = 0; e < 8; ++e) {
                unsigned short th, tl;
                split2(rp[e], th, tl);
                a_h[e] = (short)th; a_l[e] = (short)tl;
            }
            const int bo = (wid * 16 + lc) * 64 + ks * 32 + kg8;
            bf16x8 b_h = *(const bf16x8*)&Dhc[bo];
            bf16x8 b_l = *(const bf16x8*)&Dlc[bo];
            g = MFMA(a_h, b_h, g);
            g = MFMA(a_l, b_h, g);
            g = MFMA(a_h, b_l, g);
        }
        #pragma unroll
        for (int r = 0; r < 4; ++r) {
            const size_t o = (size_t)(i0 + rb + r) * TSEQ + j0 + wid * 16 + lc;
            unsigned short th, tl;
            split2(g[r], th, tl);
            Gh[o] = th; Gl[o] = tl;
        }
        __syncthreads();   // drain stores: visible to next c's A-staging loads
    }
}

// ---------------- S -= G @ Mk (pre-split operands, pure-load MFMA) ----------------
__global__ __launch_bounds__(256) void s_update_ps(float* __restrict__ S,
    const unsigned short* __restrict__ Gh_, const unsigned short* __restrict__ Gl_,
    const unsigned short* __restrict__ MktH, const unsigned short* __restrict__ MktL)
{
    const int jt = blockIdx.x, it = blockIdx.y, hh = blockIdx.z;
    if (jt > it) return;
    const unsigned short* Gh = Gh_ + (size_t)hh * TSEQ * TSEQ;
    const unsigned short* Gl = Gl_ + (size_t)hh * TSEQ * TSEQ;
    const unsigned short* Mh = MktH + (size_t)hh * TSEQ * TSEQ;
    const unsigned short* Ml = MktL + (size_t)hh * TSEQ * TSEQ;
    float* Sh = S + (size_t)hh * TSEQ * TSEQ;
    __shared__ unsigned short Ah[64][72], Al[64][72], Bh[64][72], Bl[64][72];
    const int tid = threadIdx.x;
    const int i0 = it * 64, j0 = jt * 64;
    const int srow = tid >> 2, sc = tid & 3;
    const int lane = tid & 63, wid = tid >> 6;
    const int lc = lane & 15, kg8 = (lane >> 4) * 8;
    f32x4 acc[4] = {{0.f,0.f,0.f,0.f},{0.f,0.f,0.f,0.f},{0.f,0.f,0.f,0.f},{0.f,0.f,0.f,0.f}};
    for (int st = jt; st <= it; ++st) {
        const int s0 = st * 64;
        __syncthreads();
        const size_t ab = (size_t)(i0 + srow) * TSEQ + s0;
        const size_t bb = (size_t)(j0 + srow) * TSEQ + s0;
        *(uint4*)&Ah[srow][sc * 8]       = *(const uint4*)&Gh[ab + sc * 8];
        *(uint4*)&Ah[srow][(sc + 4) * 8] = *(const uint4*)&Gh[ab + (sc + 4) * 8];
        *(uint4*)&Al[srow][sc * 8]       = *(const uint4*)&Gl[ab + sc * 8];
        *(uint4*)&Al[srow][(sc + 4) * 8] = *(const uint4*)&Gl[ab + (sc + 4) * 8];
        *(uint4*)&Bh[srow][sc * 8]       = *(const uint4*)&Mh[bb + sc * 8];
        *(uint4*)&Bh[srow][(sc + 4) * 8] = *(const uint4*)&Mh[bb + (sc + 4) * 8];
        *(uint4*)&Bl[srow][sc * 8]       = *(const uint4*)&Ml[bb + sc * 8];
        *(uint4*)&Bl[srow][(sc + 4) * 8] = *(const uint4*)&Ml[bb + (sc + 4) * 8];
        __syncthreads();
        #pragma unroll
        for (int ks = 0; ks < 2; ++ks) {
            bf16x8 a_h = *(const bf16x8*)&Ah[wid * 16 + lc][ks * 32 + kg8];
            bf16x8 a_l = *(const bf16x8*)&Al[wid * 16 + lc][ks * 32 + kg8];
            #pragma unroll
            for (int nt = 0; nt < 4; ++nt) {
                bf16x8 b_h = *(const bf16x8*)&Bh[nt * 16 + lc][ks * 32 + kg8];
                bf16x8 b_l = *(const bf16x8*)&Bl[nt * 16 + lc][ks * 32 + kg8];
                acc[nt] = MFMA(a_h, b_h, acc[nt]);
                acc[nt] = MFMA(a_l, b_h, acc[nt]);
                acc[nt] = MFMA(a_h, b_l, acc[nt]);
            }
        }
    }
    const int orow = i0 + wid * 16 + (lane >> 4) * 4;
    #pragma unroll
    for (int nt = 0; nt < 4; ++nt)
        #pragma unroll
        for (int r = 0; r < 4; ++r)
            Sh[(size_t)(orow + r) * TSEQ + j0 + nt * 16 + lc] -= acc[nt][r];
}

// ---------------- generic fp32 tiled GEMM (kept for K=32 wpre) ----------------
__global__ __launch_bounds__(256) void gemm_f32(const float* __restrict__ A,
    const float* __restrict__ B, float* __restrict__ C, int M, int N, int K)
{
    __shared__ float At[16][68];
    __shared__ float Bs[16][68];
    const int tid = threadIdx.x;
    const int tx = tid & 15, ty = tid >> 4;
    const int i0 = blockIdx.y * 64, j0 = blockIdx.x * 64;
    const int arow = tid >> 2, ac4 = (tid & 3) * 4;
    const int brow = tid >> 4, bc4 = (tid & 15) * 4;
    float acc[4][4] = {};
    for (int k0 = 0; k0 < K; k0 += 16) {
        float4 a = *(const float4*)&A[(size_t)(i0 + arow) * K + k0 + ac4];
        At[ac4 + 0][arow] = a.x; At[ac4 + 1][arow] = a.y;
        At[ac4 + 2][arow] = a.z; At[ac4 + 3][arow] = a.w;
        *(float4*)&Bs[brow][bc4] = *(const float4*)&B[(size_t)(k0 + brow) * N + j0 + bc4];
        __syncthreads();
        #pragma unroll
        for (int kk = 0; kk < 16; ++kk) {
            float4 a4 = *(const float4*)&At[kk][ty * 4];
            float4 b4 = *(const float4*)&Bs[kk][tx * 4];
            float av[4] = {a4.x, a4.y, a4.z, a4.w};
            float bv[4] = {b4.x, b4.y, b4.z, b4.w};
            #pragma unroll
            for (int m = 0; m < 4; ++m)
                #pragma unroll
                for (int n = 0; n < 4; ++n)
                    acc[m][n] = fmaf(av[m], bv[n], acc[m][n]);
        }
        __syncthreads();
    }
    #pragma unroll
    for (int m = 0; m < 4; ++m) {
        float4 o = {acc[m][0], acc[m][1], acc[m][2], acc[m][3]};
        *(float4*)&C[(size_t)(i0 + ty * 4 + m) * N + j0 + tx * 4] = o;
    }
}

// ---------------- skinny GEMM (N in {16,32}): row-parallel split-K ----------------
__global__ __launch_bounds__(256) void gemm_skinny_rows(const float* __restrict__ A,
    const float* __restrict__ B, float* __restrict__ C, int N, int K)
{
    const int row = blockIdx.x;
    const int tid = threadIdx.x;
    const int col = tid & (N - 1);
    const int ks = tid / N;
    const int nsl = 256 / N;
    const float* a = A + (size_t)row * K;
    float s = 0.f;
    for (int k = ks; k < K; k += nsl)
        s = fmaf(a[k], B[(size_t)k * N + col], s);
    __shared__ float red[256];
    red[tid] = s; __syncthreads();
    for (int off = 128; off >= N; off >>= 1) {
        if (tid < off) red[tid] += red[tid + off];
        __syncthreads();
    }
    if (tid < N) C[(size_t)row * N + col] = red[tid];
}

// ---------------- causal depthwise conv(3) + SiLU + per-head L2 norm + beta -------
__global__ __launch_bounds__(64) void conv_silu_norm(const float* __restrict__ wpre,
    const float* __restrict__ cw, const float* __restrict__ blog,
    float* __restrict__ w, float* __restrict__ beta)
{
    const int t = blockIdx.x, h = blockIdx.y, d = threadIdx.x;
    const int c = h * HD + d;
    float x2 = wpre[(size_t)t * DMODEL + c];
    float x1 = (t >= 1) ? wpre[(size_t)(t - 1) * DMODEL + c] : 0.f;
    float x0 = (t >= 2) ? wpre[(size_t)(t - 2) * DMODEL + c] : 0.f;
    float y = cw[c * 3 + 0] * x0 + cw[c * 3 + 1] * x1 + cw[c * 3 + 2] * x2;
    y = y / (1.f + expf(-y));
    float ss = y * y;
    #pragma unroll
    for (int off = 32; off >= 1; off >>= 1) ss += __shfl_xor(ss, off, 64);
    float r = 1.f / sqrtf(ss + 1e-6f);
    w[(size_t)t * DMODEL + c] = y * r;
    if (d == 0) beta[t * NH + h] = 2.f / (1.f + expf(-blog[t * NH + h]));
}

// ---------------- causal row softmax with D^-0.5 scaling, in place ----------------
__global__ __launch_bounds__(256) void softmax_causal(float* __restrict__ S)
{
    const int i = blockIdx.x, hh = blockIdx.y;
    float* row = S + (size_t)hh * TSEQ * TSEQ + (size_t)i * TSEQ;
    const int tid = threadIdx.x;
    const float sc = 0.125f;
    __shared__ float red[256];
    float mx = -3.4e38f;
    for (int j = tid; j <= i; j += 256) mx = fmaxf(mx, row[j] * sc);
    red[tid] = mx; __syncthreads();
    for (int off = 128; off >= 1; off >>= 1) {
        if (tid < off) red[tid] = fmaxf(red[tid], red[tid + off]);
        __syncthreads();
    }
    mx = red[0]; __syncthreads();
    float sum = 0.f;
    for (int j = tid; j <= i; j += 256) {
        float e = expf(row[j] * sc - mx);
        row[j] = e; sum += e;
    }
    red[tid] = sum; __syncthreads();
    for (int off = 128; off >= 1; off >>= 1) {
        if (tid < off) red[tid] += red[tid + off];
        __syncthreads();
    }
    float inv = 1.f / red[0];
    for (int j = tid; j <= i; j += 256) row[j] *= inv;
}

// ---------------- O[head slice] = P @ V ----------------
__global__ __launch_bounds__(256) void pv64(const float* __restrict__ P,
    const float* __restrict__ V, float* __restrict__ O)
{
    const int it = blockIdx.x, hh = blockIdx.y;
    const float* Ph = P + (size_t)hh * TSEQ * TSEQ;
    __shared__ float Pt[64][68];
    __shared__ float Vs[64][68];
    const int tid = threadIdx.x, tx = tid & 15, ty = tid >> 4;
    const int i0 = it * 64;
    const int row = tid >> 2, c4 = (tid & 3) * 4;
    float acc[4][4] = {};
    for (int jt = 0; jt <= it; ++jt) {
        const int j0 = jt * 64;
        const int i = i0 + row;
        #pragma unroll
        for (int p = 0; p < 4; ++p) {
            int dd = c4 + p * 16;
            float4 pv = *(const float4*)&Ph[(size_t)i * TSEQ + j0 + dd];
            Pt[dd + 0][row] = (j0 + dd + 0 <= i) ? pv.x : 0.f;
            Pt[dd + 1][row] = (j0 + dd + 1 <= i) ? pv.y : 0.f;
            Pt[dd + 2][row] = (j0 + dd + 2 <= i) ? pv.z : 0.f;
            Pt[dd + 3][row] = (j0 + dd + 3 <= i) ? pv.w : 0.f;
            *(float4*)&Vs[row][dd] = *(const float4*)&V[(size_t)(j0 + row) * DMODEL + hh * HD + dd];
        }
        __syncthreads();
        #pragma unroll 8
        for (int kk = 0; kk < 64; ++kk) {
            float4 a4 = *(const float4*)&Pt[kk][ty * 4];
            float4 b4 = *(const float4*)&Vs[kk][tx * 4];
            float av[4] = {a4.x, a4.y, a4.z, a4.w};
            float bv[4] = {b4.x, b4.y, b4.z, b4.w};
            #pragma unroll
            for (int m = 0; m < 4; ++m)
                #pragma unroll
                for (int n = 0; n < 4; ++n)
                    acc[m][n] = fmaf(av[m], bv[n], acc[m][n]);
        }
        __syncthreads();
    }
    #pragma unroll
    for (int m = 0; m < 4; ++m) {
        float4 o = {acc[m][0], acc[m][1], acc[m][2], acc[m][3]};
        *(float4*)&O[(size_t)(i0 + ty * 4 + m) * DMODEL + hh * HD + tx * 4] = o;
    }
}

extern "C" void kernel_launch(void* const* d_in, const int* in_sizes, int n_in,
                              void* d_out, int out_size, void* d_ws, size_t ws_size,
                              hipStream_t stream)
{
    const float* x   = (const float*)d_in[0];
    const float* Wq  = (const float*)d_in[1];
    const float* Wk  = (const float*)d_in[2];
    const float* Wv  = (const float*)d_in[3];
    const float* Ww1 = (const float*)d_in[4];
    const float* Ww2 = (const float*)d_in[5];
    const float* cw  = (const float*)d_in[6];
    const float* Wb  = (const float*)d_in[7];
    const float* Wo  = (const float*)d_in[8];
    float* out = (float*)d_out;

    float* ws = (float*)d_ws;
    size_t off = 0;
    auto alloc = [&](size_t n) { float* p = ws + off; off += n; return p; };
    float* q    = alloc((size_t)TSEQ * DMODEL);
    float* k    = alloc((size_t)TSEQ * DMODEL);
    float* v    = alloc((size_t)TSEQ * DMODEL);
    float* w    = alloc((size_t)TSEQ * DMODEL);
    float* wpre = alloc((size_t)TSEQ * DMODEL);   // reused as Dinv hi/lo after conv
    float* oatt = alloc((size_t)TSEQ * DMODEL);
    float* xw1  = alloc((size_t)TSEQ * RANK);
    float* blog = alloc((size_t)TSEQ * NH);
    float* beta = alloc((size_t)TSEQ * NH);

    const size_t HT = (size_t)NH * TSEQ * TSEQ;
    float* slot0 = ws + off;
    float* slot1 = slot0 + HT;
    float* slot2 = slot1 + HT;
    unsigned short* MtH = (unsigned short*)slot1;
    unsigned short* MtL = MtH + HT;
    unsigned short* GH  = (unsigned short*)slot2;
    unsigned short* GL  = GH + HT;
    unsigned short* DtH = (unsigned short*)wpre;
    unsigned short* DtL = DtH + (size_t)NH * 16 * 4096;

    const size_t E = (size_t)TSEQ * DMODEL;
    unsigned short* us = (unsigned short*)slot0;
    unsigned short* xs_h  = us;          unsigned short* xs_l  = us + E;
    unsigned short* wqt_h = us + 2 * E;  unsigned short* wqt_l = us + 3 * E;
    unsigned short* wkt_h = us + 4 * E;  unsigned short* wkt_l = us + 5 * E;
    unsigned short* wvt_h = us + 6 * E;  unsigned short* wvt_l = us + 7 * E;
    unsigned short* oat_h = us;          unsigned short* oat_l = us + E;
    unsigned short* wot_h = us + 2 * E;  unsigned short* wot_l = us + 3 * E;

    dim3 g64(DMODEL / 64, TSEQ / 64);
    dim3 gt(16, 16);
    dim3 gp(16, 16, NH);

    // --- projections via split-bf16 MFMA ---
    split_rm<<<(int)(E / 4 + 255) / 256, 256, 0, stream>>>(x, xs_h, xs_l, (int)(E / 4));
    split_tr<<<gt, 256, 0, stream>>>(Wq, wqt_h, wqt_l, DMODEL, DMODEL);
    split_tr<<<gt, 256, 0, stream>>>(Wk, wkt_h, wkt_l, DMODEL, DMODEL);
    split_tr<<<gt, 256, 0, stream>>>(Wv, wvt_h, wvt_l, DMODEL, DMODEL);
    mfma_nt<<<g64, 256, 0, stream>>>(xs_h, xs_l, DMODEL, wqt_h, wqt_l, DMODEL, q, DMODEL, DMODEL);
    mfma_nt<<<g64, 256, 0, stream>>>(xs_h, xs_l, DMODEL, wkt_h, wkt_l, DMODEL, k, DMODEL, DMODEL);
    mfma_nt<<<g64, 256, 0, stream>>>(xs_h, xs_l, DMODEL, wvt_h, wvt_l, DMODEL, v, DMODEL, DMODEL);
    gemm_skinny_rows<<<TSEQ, 256, 0, stream>>>(x, Ww1, xw1, RANK, DMODEL);
    gemm_f32<<<g64, 256, 0, stream>>>(xw1, Ww2, wpre, TSEQ, DMODEL, RANK);
    gemm_skinny_rows<<<TSEQ, 256, 0, stream>>>(x, Wb, blog, NH, DMODEL);
    conv_silu_norm<<<dim3(TSEQ, NH), 64, 0, stream>>>(wpre, cw, blog, w, beta);

    // --- UT-transform path ---
    pairwise_mt<<<gp, 256, 0, stream>>>(w, w, beta, MtH, MtL);        // Mt, split
    diag_inv<<<dim3(16, NH), 64, 0, stream>>>(MtH, MtL, DtH, DtL);    // Dinv^T per diag block
    pairwise_mfma<<<gp, 256, 0, stream>>>(q, w, slot0);               // QW (causal, fp32)
    solve_row16<<<dim3(TSEQ / 16, NH), 256, 0, stream>>>(slot0, MtH, MtL, DtH, DtL, GH, GL);
    pairwise_mt<<<gp, 256, 0, stream>>>(w, k, beta, MtH, MtL);        // Mkt (reuses slot1)
    pairwise_mfma<<<gp, 256, 0, stream>>>(q, k, slot0);               // S = QK (reuses slot0)
    s_update_ps<<<gp, 256, 0, stream>>>(slot0, GH, GL, MtH, MtL);     // S -= G Mk
    softmax_causal<<<dim3(TSEQ, NH), 256, 0, stream>>>(slot0);
    pv64<<<dim3(16, NH), 256, 0, stream>>>(slot0, v, oatt);

    // --- final projection via split-bf16 MFMA (slot0 dead -> overlay splits) ---
    split_rm<<<(int)(E / 4 + 255) / 256, 256, 0, stream>>>(oatt, oat_h, oat_l, (int)(E / 4));
    split_tr<<<gt, 256, 0, stream>>>(Wo, wot_h, wot_l, DMODEL, DMODEL);
    mfma_nt<<<g64, 256, 0, stream>>>(oat_h, oat_l, DMODEL, wot_h, wot_l, DMODEL, out, DMODEL, DMODEL);
}